// Round 8
// baseline (207.409 us; speedup 1.0000x reference)
//
#include <hip/hip_runtime.h>
#include <math.h>

#define Nn 64
#define Tt 200
#define Bb 64

__device__ __forceinline__ float sigm(float x){ return 1.0f/(1.0f+__expf(-x)); }
__device__ __forceinline__ float tanh_fast(float x){
  x = fminf(fmaxf(x, -15.f), 15.f);
  float e = __expf(-2.f*x);
  return (1.f - e)/(1.f + e);
}

typedef __attribute__((ext_vector_type(4))) float f4;

// Opaque keep-alive: marks the 4 components as modified by asm, so the
// compiler can NEITHER rematerialize the original global load inside the
// loop NOR sink it. This is the fix for the R1/R6/R7 pattern where the
// allocator capped VGPRs (~44-72) and re-loaded loop-invariant weights
// from L2 every recurrence step (~12 loads + waits per step).
#define KEEP4(v) asm volatile("" : "+v"((v)[0]), "+v"((v)[1]), "+v"((v)[2]), "+v"((v)[3]))

// ---------------------------------------------------------------------------
// K1: build graph operators. L = -S_cheb, L2 = 2*S@S - I, G = S_gcn (+diag).
// ---------------------------------------------------------------------------
__global__ __launch_bounds__(256) void k1_graphs(
    const int* __restrict__ sp_ei, const float* __restrict__ sp_ew,
    const int* __restrict__ fn_ei, const float* __restrict__ fn_ew,
    float* __restrict__ Lg, float* __restrict__ L2g, float* __restrict__ Gm)
{
  __shared__ float deg[Nn];
  __shared__ float dinv[Nn];
  __shared__ float S[64*68];            // padded stride 68
  const int tid = threadIdx.x;

  // ---- ChebConv operator (512 edges) ----
  if (tid < Nn) deg[tid] = 0.f;
  for (int i=tid;i<64*68;i+=256) S[i]=0.f;
  __syncthreads();
  for (int e=tid;e<512;e+=256) atomicAdd(&deg[sp_ei[e]], sp_ew[e]);   // deg over row
  __syncthreads();
  if (tid < Nn) dinv[tid] = (deg[tid] > 0.f) ? rsqrtf(deg[tid]) : 0.f;
  __syncthreads();
  for (int e=tid;e<512;e+=256) {
    int r = sp_ei[e], c = sp_ei[512+e];
    atomicAdd(&S[c*68 + r], dinv[r]*sp_ew[e]*dinv[c]);
  }
  __syncthreads();
  for (int i=tid;i<4096;i+=256) Lg[i] = -S[(i>>6)*68 + (i&63)];   // Ltil = -S
  {
    const int n = tid>>2, mb = (tid&3)*16;
    float a[16];
    #pragma unroll
    for (int q=0;q<16;q++) a[q]=0.f;
    for (int j=0;j<64;j++){
      float snj = S[n*68+j];
      const float4* rj = (const float4*)&S[j*68+mb];
      #pragma unroll
      for (int q=0;q<4;q++){
        float4 v = rj[q];
        a[q*4+0]=fmaf(snj,v.x,a[q*4+0]);
        a[q*4+1]=fmaf(snj,v.y,a[q*4+1]);
        a[q*4+2]=fmaf(snj,v.z,a[q*4+2]);
        a[q*4+3]=fmaf(snj,v.w,a[q*4+3]);
      }
    }
    #pragma unroll
    for (int q=0;q<16;q++){
      int m = mb+q;
      L2g[n*64+m] = 2.f*a[q] - (n==m ? 1.f : 0.f);
    }
  }
  __syncthreads();   // all reads of S done before reuse

  // ---- GCNConv operator (1024 edges) ----
  if (tid < Nn) deg[tid] = 0.f;
  for (int i=tid;i<64*68;i+=256) S[i]=0.f;
  __syncthreads();
  for (int e=tid;e<1024;e+=256) atomicAdd(&deg[fn_ei[1024+e]], fn_ew[e]);  // deg over col
  __syncthreads();
  if (tid < Nn) dinv[tid] = rsqrtf(deg[tid] + 1.f);
  __syncthreads();
  for (int e=tid;e<1024;e+=256) {
    int r = fn_ei[e], c = fn_ei[1024+e];
    atomicAdd(&S[c*68 + r], dinv[r]*fn_ew[e]*dinv[c]);
  }
  __syncthreads();
  if (tid < Nn) S[tid*68 + tid] += dinv[tid]*dinv[tid];     // + diag(1/deg)
  __syncthreads();
  for (int i=tid;i<4096;i+=256) Gm[i] = S[(i>>6)*68 + (i&63)];
}

// ---------------------------------------------------------------------------
// K2: fold Wih (+Wcheb/Wgcn/graph ops) into Aeff[384][64] and constv[384].
// ---------------------------------------------------------------------------
__global__ __launch_bounds__(64) void k2_aeff(
    const float* __restrict__ Wih_f, const float* __restrict__ bih_f,
    const float* __restrict__ Wih_b, const float* __restrict__ bih_b,
    const float* __restrict__ Wcheb, const float* __restrict__ bcheb,
    const float* __restrict__ Wgcn,  const float* __restrict__ bgcn,
    const float* __restrict__ Lg, const float* __restrict__ L2g,
    const float* __restrict__ Gm,
    float* __restrict__ Aeff, float* __restrict__ constv)
{
  const int g = blockIdx.x;                 // 0..383
  const int dir = (g >= 192) ? 1 : 0;
  const int grow = dir ? g - 192 : g;
  const float* Wih = dir ? Wih_b : Wih_f;
  const float* bih = dir ? bih_b : bih_f;

  __shared__ float wrow[64*129];
  __shared__ float arow[256];
  const int tid = threadIdx.x;              // 64 threads = 1 wave

  for (int i = tid; i < 8192; i += 64)
    wrow[(i>>7)*129 + (i&127)] = Wih[grow*8192 + i];
  __syncthreads();

  const int n = tid;
  float a0=0.f,a1=0.f,a2=0.f,a3=0.f,cp=0.f;
  for (int c=0;c<64;c++) {
    float w1 = wrow[n*129 + c];
    a0 = fmaf(w1, Wcheb[c],     a0);
    a1 = fmaf(w1, Wcheb[64+c],  a1);
    a2 = fmaf(w1, Wcheb[128+c], a2);
    cp = fmaf(w1, bcheb[c],     cp);
    float w2 = wrow[n*129 + 64 + c];
    a3 = fmaf(w2, Wgcn[c], a3);
    cp = fmaf(w2, bgcn[c], cp);
  }
  arow[n*4+0]=a0; arow[n*4+1]=a1; arow[n*4+2]=a2; arow[n*4+3]=a3;
  for (int off=32; off; off>>=1) cp += __shfl_down(cp, off, 64);
  if (tid==0) constv[g] = cp + bih[grow];
  __syncthreads();

  const int m = tid;
  float ae = arow[m*4+0];
  for (int nn2=0; nn2<64; nn2++) {
    ae = fmaf(arow[nn2*4+1], Lg [nn2*64+m], ae);
    ae = fmaf(arow[nn2*4+2], L2g[nn2*64+m], ae);
    ae = fmaf(arow[nn2*4+3], Gm [nn2*64+m], ae);
  }
  Aeff[g*64+m] = ae;
}

// ---------------------------------------------------------------------------
// K3: transpose x[B][N][T] -> xTr[B*T][N]
// ---------------------------------------------------------------------------
__global__ __launch_bounds__(256) void k3_transpose(
    const float* __restrict__ x, float* __restrict__ xTr)
{
  const int b = blockIdx.x;
  for (int idx = threadIdx.x; idx < Tt*Nn; idx += 256) {
    int t = idx >> 6, m = idx & 63;
    xTr[(b*Tt + t)*64 + m] = x[(b*64 + m)*Tt + t];
  }
}

// ---------------------------------------------------------------------------
// K4: xp[12800][384] = xTr[12800][64] @ Aeff[384][64]^T + constv
// ---------------------------------------------------------------------------
__global__ __launch_bounds__(256) void k4_gemm(
    const float* __restrict__ xTr, const float* __restrict__ Aeff,
    const float* __restrict__ constv, float* __restrict__ xp)
{
  const int m0 = blockIdx.x*64, g0 = blockIdx.y*64;
  __shared__ float sX[64*68];
  __shared__ float sA[64*68];
  const int tid = threadIdx.x;
  const float4* xTr4 = (const float4*)xTr;
  const float4* A4   = (const float4*)Aeff;

  #pragma unroll
  for (int i=0;i<4;i++) {
    int f = tid + i*256;
    int row = f >> 4, kq = f & 15;
    float4 v = xTr4[(m0+row)*16 + kq];
    float vv[4] = {v.x,v.y,v.z,v.w};
    float4 w = A4[(g0+row)*16 + kq];
    float wv[4] = {w.x,w.y,w.z,w.w};
    #pragma unroll
    for (int q=0;q<4;q++) {
      sX[(kq*4+q)*68 + row] = vv[q];
      sA[(kq*4+q)*68 + row] = wv[q];
    }
  }
  __syncthreads();

  const int tm = tid & 15, tn = tid >> 4;
  float acc[4][4] = {};
  #pragma unroll 8
  for (int k=0;k<64;k++) {
    float4 a  = *(const float4*)&sX[k*68 + tm*4];
    float4 bb = *(const float4*)&sA[k*68 + tn*4];
    float av[4]={a.x,a.y,a.z,a.w}, bv[4]={bb.x,bb.y,bb.z,bb.w};
    #pragma unroll
    for (int i=0;i<4;i++)
      #pragma unroll
      for (int j=0;j<4;j++)
        acc[i][j] = fmaf(av[i], bv[j], acc[i][j]);
  }

  float cv[4];
  #pragma unroll
  for (int j=0;j<4;j++) cv[j] = constv[g0 + tn*4 + j];
  #pragma unroll
  for (int i=0;i<4;i++) {
    int mrow = m0 + tm*4 + i;
    #pragma unroll
    for (int j=0;j<4;j++)
      xp[mrow*384 + g0 + tn*4 + j] = acc[i][j] + cv[j];
  }
}

// ---------------------------------------------------------------------------
// K5: biGRU recurrence. 128 blocks = (b,dir); 256 threads (4 waves).
// R7 structure + KEEP4 opaque-asm residency fix (weights provably cannot be
// rematerialized from memory inside the loop) + prefetch issued at the TOP
// of each step so L3 latency overlaps matvec/shuffle/gates instead of
// stalling the end-of-step barrier drain.
// ---------------------------------------------------------------------------
__global__ __launch_bounds__(256, 1) void k5_gru(
    const float* __restrict__ xp,
    const float* __restrict__ Whh_f, const float* __restrict__ bhh_f,
    const float* __restrict__ Whh_b, const float* __restrict__ bhh_b,
    float* __restrict__ gru_out)
{
  const int bd = blockIdx.x;
  const int b = bd >> 1, dir = bd & 1;
  const int tid = threadIdx.x;
  const int w  = tid >> 6;              // wave 0..3
  const int l  = tid & 63;
  const int u  = l & 15;                // unit-in-wave
  const int s  = l >> 4;                // segment 0..3
  const int ug = w*16 + u;              // global hidden unit 0..63
  const float* Whh = dir ? Whh_b : Whh_f;
  const float* bhh = dir ? bhh_b : bhh_f;

  // resident weights: rows {ug, 64+ug, 128+ug}, cols 16s..16s+15
  f4 wr0 = ((const f4*)(Whh + (size_t)(      ug)*64 + 16*s))[0];
  f4 wr1 = ((const f4*)(Whh + (size_t)(      ug)*64 + 16*s))[1];
  f4 wr2 = ((const f4*)(Whh + (size_t)(      ug)*64 + 16*s))[2];
  f4 wr3 = ((const f4*)(Whh + (size_t)(      ug)*64 + 16*s))[3];
  f4 wz0 = ((const f4*)(Whh + (size_t)( 64 + ug)*64 + 16*s))[0];
  f4 wz1 = ((const f4*)(Whh + (size_t)( 64 + ug)*64 + 16*s))[1];
  f4 wz2 = ((const f4*)(Whh + (size_t)( 64 + ug)*64 + 16*s))[2];
  f4 wz3 = ((const f4*)(Whh + (size_t)( 64 + ug)*64 + 16*s))[3];
  f4 wn0 = ((const f4*)(Whh + (size_t)(128 + ug)*64 + 16*s))[0];
  f4 wn1 = ((const f4*)(Whh + (size_t)(128 + ug)*64 + 16*s))[1];
  f4 wn2 = ((const f4*)(Whh + (size_t)(128 + ug)*64 + 16*s))[2];
  f4 wn3 = ((const f4*)(Whh + (size_t)(128 + ug)*64 + 16*s))[3];
  KEEP4(wr0); KEEP4(wr1); KEEP4(wr2); KEEP4(wr3);
  KEEP4(wz0); KEEP4(wz1); KEEP4(wz2); KEEP4(wz3);
  KEEP4(wn0); KEEP4(wn1); KEEP4(wn2); KEEP4(wn3);
  float br_ = bhh[ug], bz_ = bhh[64+ug], bn_ = bhh[128+ug];
  asm volatile("" : "+v"(br_), "+v"(bz_), "+v"(bn_));

  __shared__ __align__(16) float hbuf[2][64];
  if (tid < 64) { hbuf[0][tid] = 0.f; hbuf[1][tid] = 0.f; }
  float hprev = 0.f;

  const int t0 = dir ? (Tt-1) : 0;
  const int tstep = dir ? -1 : 1;
  const float* xb = xp + (size_t)(b*Tt)*384 + dir*192 + ug;
  float* gout = gru_out + (size_t)(b*Tt)*128 + dir*64 + ug;

  float xrA = xb[(size_t)t0*384], xzA = xb[(size_t)t0*384+64], xnA = xb[(size_t)t0*384+128];
  const int t1 = t0 + tstep;
  float xrB = xb[(size_t)t1*384], xzB = xb[(size_t)t1*384+64], xnB = xb[(size_t)t1*384+128];
  __syncthreads();                       // hbuf init + first prefetch visible

  int t = t0;
  auto STEP = [&](float& xr, float& xz, float& xn, int rb){
    // consume this step's x-parts, then immediately issue the t+2 reload so
    // its latency overlaps the matvec/shuffles/gates below.
    const float cxr=xr, cxz=xz, cxn=xn;
    const int tpre = t + 2*tstep;
    if ((unsigned)tpre < (unsigned)Tt) {
      xr = xb[(size_t)tpre*384];
      xz = xb[(size_t)tpre*384+64];
      xn = xb[(size_t)tpre*384+128];
    }

    const f4* hp = (const f4*)&hbuf[rb][16*s];
    float ar=0.f, az=0.f, an=0.f;
    {
      f4 hv;
      hv = hp[0];
      ar=fmaf(wr0.x,hv.x,ar); ar=fmaf(wr0.y,hv.y,ar); ar=fmaf(wr0.z,hv.z,ar); ar=fmaf(wr0.w,hv.w,ar);
      az=fmaf(wz0.x,hv.x,az); az=fmaf(wz0.y,hv.y,az); az=fmaf(wz0.z,hv.z,az); az=fmaf(wz0.w,hv.w,az);
      an=fmaf(wn0.x,hv.x,an); an=fmaf(wn0.y,hv.y,an); an=fmaf(wn0.z,hv.z,an); an=fmaf(wn0.w,hv.w,an);
      hv = hp[1];
      ar=fmaf(wr1.x,hv.x,ar); ar=fmaf(wr1.y,hv.y,ar); ar=fmaf(wr1.z,hv.z,ar); ar=fmaf(wr1.w,hv.w,ar);
      az=fmaf(wz1.x,hv.x,az); az=fmaf(wz1.y,hv.y,az); az=fmaf(wz1.z,hv.z,az); az=fmaf(wz1.w,hv.w,az);
      an=fmaf(wn1.x,hv.x,an); an=fmaf(wn1.y,hv.y,an); an=fmaf(wn1.z,hv.z,an); an=fmaf(wn1.w,hv.w,an);
      hv = hp[2];
      ar=fmaf(wr2.x,hv.x,ar); ar=fmaf(wr2.y,hv.y,ar); ar=fmaf(wr2.z,hv.z,ar); ar=fmaf(wr2.w,hv.w,ar);
      az=fmaf(wz2.x,hv.x,az); az=fmaf(wz2.y,hv.y,az); az=fmaf(wz2.z,hv.z,az); az=fmaf(wz2.w,hv.w,az);
      an=fmaf(wn2.x,hv.x,an); an=fmaf(wn2.y,hv.y,an); an=fmaf(wn2.z,hv.z,an); an=fmaf(wn2.w,hv.w,an);
      hv = hp[3];
      ar=fmaf(wr3.x,hv.x,ar); ar=fmaf(wr3.y,hv.y,ar); ar=fmaf(wr3.z,hv.z,ar); ar=fmaf(wr3.w,hv.w,ar);
      az=fmaf(wz3.x,hv.x,az); az=fmaf(wz3.y,hv.y,az); az=fmaf(wz3.z,hv.z,az); az=fmaf(wz3.w,hv.w,az);
      an=fmaf(wn3.x,hv.x,an); an=fmaf(wn3.y,hv.y,an); an=fmaf(wn3.z,hv.z,an); an=fmaf(wn3.w,hv.w,an);
    }
    // cross-segment butterfly: all 4 copies end with the full sums
    ar += __shfl_xor(ar,16,64); az += __shfl_xor(az,16,64); an += __shfl_xor(an,16,64);
    ar += __shfl_xor(ar,32,64); az += __shfl_xor(az,32,64); an += __shfl_xor(an,32,64);

    float r    = sigm(cxr + ar + br_);
    float z    = sigm(cxz + az + bz_);
    float nn2  = tanh_fast(cxn + r*(an + bn_));
    float hnew = (1.f - z)*nn2 + z*hprev;
    hprev = hnew;                            // identical on all 4 copies
    if (s == 0) {
      hbuf[rb^1][ug] = hnew;
      gout[(size_t)t*128] = hnew;
    }
    t += tstep;
    __syncthreads();                         // hnew visible for next step
  };

  for (int sp=0; sp<Tt; sp+=2) { STEP(xrA,xzA,xnA,0); STEP(xrB,xzB,xnB,1); }
}

// ---------------------------------------------------------------------------
// K6: attention pooling + classifier. One block per batch item.
// ---------------------------------------------------------------------------
__global__ __launch_bounds__(256) void k6_attn(
    const float* __restrict__ gru_out,
    const float* __restrict__ attn_W, const float* __restrict__ attn_b,
    const float* __restrict__ clf_W,  const float* __restrict__ clf_b,
    float* __restrict__ out)
{
  const int b = blockIdx.x, tid = threadIdx.x;
  __shared__ float s_s[Tt];
  __shared__ float red[256];
  __shared__ float aW[128], cW[128];
  if (tid < 128) { aW[tid]=attn_W[tid]; cW[tid]=clf_W[tid]; }
  __syncthreads();

  if (tid < Tt) {
    const float* row = gru_out + (b*Tt + tid)*128;
    float acc = 0.f;
    for (int j=0;j<128;j++) acc = fmaf(row[j], aW[j], acc);
    s_s[tid] = tanhf(acc + attn_b[0]);
  }
  __syncthreads();

  red[tid] = (tid < Tt) ? s_s[tid] : -1e30f;
  __syncthreads();
  for (int s2=128;s2;s2>>=1){ if(tid<s2) red[tid]=fmaxf(red[tid],red[tid+s2]); __syncthreads(); }
  float mx = red[0];
  __syncthreads();

  float e = 0.f;
  if (tid < Tt) { e = expf(s_s[tid]-mx); s_s[tid] = e; }
  red[tid] = e;
  __syncthreads();
  for (int s2=128;s2;s2>>=1){ if(tid<s2) red[tid]+=red[tid+s2]; __syncthreads(); }
  float total = red[0];
  __syncthreads();

  float p = 0.f;
  if (tid < 128) {
    float c = 0.f;
    for (int t=0;t<Tt;t++) c = fmaf(s_s[t], gru_out[(b*Tt+t)*128 + tid], c);
    p = (c/total)*cW[tid];
  }
  red[tid] = p;
  __syncthreads();
  for (int s2=128;s2;s2>>=1){ if(tid<s2) red[tid]+=red[tid+s2]; __syncthreads(); }
  if (tid==0) out[b] = sigm(red[0] + clf_b[0]);
}

// ---------------------------------------------------------------------------
extern "C" void kernel_launch(void* const* d_in, const int* in_sizes, int n_in,
                              void* d_out, int out_size, void* d_ws, size_t ws_size,
                              hipStream_t stream)
{
  const float* x      = (const float*)d_in[0];
  const int*   sp_ei  = (const int*)  d_in[1];
  const float* sp_ew  = (const float*)d_in[2];
  const int*   fn_ei  = (const int*)  d_in[3];
  const float* fn_ew  = (const float*)d_in[4];
  const float* Wcheb  = (const float*)d_in[5];
  const float* bcheb  = (const float*)d_in[6];
  const float* Wgcn   = (const float*)d_in[7];
  const float* bgcn   = (const float*)d_in[8];
  const float* Wih_f  = (const float*)d_in[9];
  const float* Whh_f  = (const float*)d_in[10];
  const float* bih_f  = (const float*)d_in[11];
  const float* bhh_f  = (const float*)d_in[12];
  const float* Wih_b  = (const float*)d_in[13];
  const float* Whh_b  = (const float*)d_in[14];
  const float* bih_b  = (const float*)d_in[15];
  const float* bhh_b  = (const float*)d_in[16];
  const float* attn_W = (const float*)d_in[17];
  const float* attn_b = (const float*)d_in[18];
  const float* clf_W  = (const float*)d_in[19];
  const float* clf_b  = (const float*)d_in[20];
  float* out = (float*)d_out;

  float* ws     = (float*)d_ws;
  float* Lg     = ws;                    // 4096
  float* L2g    = Lg   + 4096;           // 4096
  float* Gm     = L2g  + 4096;           // 4096
  float* Aeff   = Gm   + 4096;           // 384*64 = 24576
  float* constv = Aeff + 24576;          // 384 (+pad to 512)
  float* xTr    = constv + 512;          // 12800*64 = 819200
  float* xp     = xTr  + 819200;         // 12800*384 = 4915200
  float* gro    = xp   + 4915200;        // 12800*128 = 1638400

  hipLaunchKernelGGL(k1_graphs,    dim3(1),      dim3(256), 0, stream,
                     sp_ei, sp_ew, fn_ei, fn_ew, Lg, L2g, Gm);
  hipLaunchKernelGGL(k3_transpose, dim3(64),     dim3(256), 0, stream, x, xTr);
  hipLaunchKernelGGL(k2_aeff,      dim3(384),    dim3(64),  0, stream,
                     Wih_f, bih_f, Wih_b, bih_b, Wcheb, bcheb, Wgcn, bgcn,
                     Lg, L2g, Gm, Aeff, constv);
  hipLaunchKernelGGL(k4_gemm,      dim3(200, 6), dim3(256), 0, stream,
                     xTr, Aeff, constv, xp);
  hipLaunchKernelGGL(k5_gru,       dim3(128),    dim3(256), 0, stream,
                     xp, Whh_f, bhh_f, Whh_b, bhh_b, gro);
  hipLaunchKernelGGL(k6_attn,      dim3(64),     dim3(256), 0, stream,
                     gro, attn_W, attn_b, clf_W, clf_b, out);
}

// Round 9
// 171.271 us; speedup vs baseline: 1.2110x; 1.2110x over previous
//
#include <hip/hip_runtime.h>
#include <math.h>

#define Nn 64
#define Tt 200
#define Bb 64

__device__ __forceinline__ float sigm(float x){ return 1.0f/(1.0f+__expf(-x)); }
__device__ __forceinline__ float tanh_fast(float x){
  x = fminf(fmaxf(x, -15.f), 15.f);
  float e = __expf(-2.f*x);
  return (1.f - e)/(1.f + e);
}

typedef __attribute__((ext_vector_type(4))) float f4;

// ---------------------------------------------------------------------------
// K1: build graph operators. L = -S_cheb, L2 = 2*S@S - I, G = S_gcn (+diag).
// ---------------------------------------------------------------------------
__global__ __launch_bounds__(256) void k1_graphs(
    const int* __restrict__ sp_ei, const float* __restrict__ sp_ew,
    const int* __restrict__ fn_ei, const float* __restrict__ fn_ew,
    float* __restrict__ Lg, float* __restrict__ L2g, float* __restrict__ Gm)
{
  __shared__ float deg[Nn];
  __shared__ float dinv[Nn];
  __shared__ float S[64*68];            // padded stride 68
  const int tid = threadIdx.x;

  // ---- ChebConv operator (512 edges) ----
  if (tid < Nn) deg[tid] = 0.f;
  for (int i=tid;i<64*68;i+=256) S[i]=0.f;
  __syncthreads();
  for (int e=tid;e<512;e+=256) atomicAdd(&deg[sp_ei[e]], sp_ew[e]);   // deg over row
  __syncthreads();
  if (tid < Nn) dinv[tid] = (deg[tid] > 0.f) ? rsqrtf(deg[tid]) : 0.f;
  __syncthreads();
  for (int e=tid;e<512;e+=256) {
    int r = sp_ei[e], c = sp_ei[512+e];
    atomicAdd(&S[c*68 + r], dinv[r]*sp_ew[e]*dinv[c]);
  }
  __syncthreads();
  for (int i=tid;i<4096;i+=256) Lg[i] = -S[(i>>6)*68 + (i&63)];   // Ltil = -S
  {
    const int n = tid>>2, mb = (tid&3)*16;
    float a[16];
    #pragma unroll
    for (int q=0;q<16;q++) a[q]=0.f;
    for (int j=0;j<64;j++){
      float snj = S[n*68+j];
      const float4* rj = (const float4*)&S[j*68+mb];
      #pragma unroll
      for (int q=0;q<4;q++){
        float4 v = rj[q];
        a[q*4+0]=fmaf(snj,v.x,a[q*4+0]);
        a[q*4+1]=fmaf(snj,v.y,a[q*4+1]);
        a[q*4+2]=fmaf(snj,v.z,a[q*4+2]);
        a[q*4+3]=fmaf(snj,v.w,a[q*4+3]);
      }
    }
    #pragma unroll
    for (int q=0;q<16;q++){
      int m = mb+q;
      L2g[n*64+m] = 2.f*a[q] - (n==m ? 1.f : 0.f);
    }
  }
  __syncthreads();   // all reads of S done before reuse

  // ---- GCNConv operator (1024 edges) ----
  if (tid < Nn) deg[tid] = 0.f;
  for (int i=tid;i<64*68;i+=256) S[i]=0.f;
  __syncthreads();
  for (int e=tid;e<1024;e+=256) atomicAdd(&deg[fn_ei[1024+e]], fn_ew[e]);  // deg over col
  __syncthreads();
  if (tid < Nn) dinv[tid] = rsqrtf(deg[tid] + 1.f);
  __syncthreads();
  for (int e=tid;e<1024;e+=256) {
    int r = fn_ei[e], c = fn_ei[1024+e];
    atomicAdd(&S[c*68 + r], dinv[r]*fn_ew[e]*dinv[c]);
  }
  __syncthreads();
  if (tid < Nn) S[tid*68 + tid] += dinv[tid]*dinv[tid];     // + diag(1/deg)
  __syncthreads();
  for (int i=tid;i<4096;i+=256) Gm[i] = S[(i>>6)*68 + (i&63)];
}

// ---------------------------------------------------------------------------
// K2: fold Wih (+Wcheb/Wgcn/graph ops) into Aeff[384][64] and constv[384].
// ---------------------------------------------------------------------------
__global__ __launch_bounds__(64) void k2_aeff(
    const float* __restrict__ Wih_f, const float* __restrict__ bih_f,
    const float* __restrict__ Wih_b, const float* __restrict__ bih_b,
    const float* __restrict__ Wcheb, const float* __restrict__ bcheb,
    const float* __restrict__ Wgcn,  const float* __restrict__ bgcn,
    const float* __restrict__ Lg, const float* __restrict__ L2g,
    const float* __restrict__ Gm,
    float* __restrict__ Aeff, float* __restrict__ constv)
{
  const int g = blockIdx.x;                 // 0..383
  const int dir = (g >= 192) ? 1 : 0;
  const int grow = dir ? g - 192 : g;
  const float* Wih = dir ? Wih_b : Wih_f;
  const float* bih = dir ? bih_b : bih_f;

  __shared__ float wrow[64*129];
  __shared__ float arow[256];
  const int tid = threadIdx.x;              // 64 threads = 1 wave

  for (int i = tid; i < 8192; i += 64)
    wrow[(i>>7)*129 + (i&127)] = Wih[grow*8192 + i];
  __syncthreads();

  const int n = tid;
  float a0=0.f,a1=0.f,a2=0.f,a3=0.f,cp=0.f;
  for (int c=0;c<64;c++) {
    float w1 = wrow[n*129 + c];
    a0 = fmaf(w1, Wcheb[c],     a0);
    a1 = fmaf(w1, Wcheb[64+c],  a1);
    a2 = fmaf(w1, Wcheb[128+c], a2);
    cp = fmaf(w1, bcheb[c],     cp);
    float w2 = wrow[n*129 + 64 + c];
    a3 = fmaf(w2, Wgcn[c], a3);
    cp = fmaf(w2, bgcn[c], cp);
  }
  arow[n*4+0]=a0; arow[n*4+1]=a1; arow[n*4+2]=a2; arow[n*4+3]=a3;
  for (int off=32; off; off>>=1) cp += __shfl_down(cp, off, 64);
  if (tid==0) constv[g] = cp + bih[grow];
  __syncthreads();

  const int m = tid;
  float ae = arow[m*4+0];
  for (int nn2=0; nn2<64; nn2++) {
    ae = fmaf(arow[nn2*4+1], Lg [nn2*64+m], ae);
    ae = fmaf(arow[nn2*4+2], L2g[nn2*64+m], ae);
    ae = fmaf(arow[nn2*4+3], Gm [nn2*64+m], ae);
  }
  Aeff[g*64+m] = ae;
}

// ---------------------------------------------------------------------------
// K3: transpose x[B][N][T] -> xTr[B*T][N]
// ---------------------------------------------------------------------------
__global__ __launch_bounds__(256) void k3_transpose(
    const float* __restrict__ x, float* __restrict__ xTr)
{
  const int b = blockIdx.x;
  for (int idx = threadIdx.x; idx < Tt*Nn; idx += 256) {
    int t = idx >> 6, m = idx & 63;
    xTr[(b*Tt + t)*64 + m] = x[(b*64 + m)*Tt + t];
  }
}

// ---------------------------------------------------------------------------
// K4: xp[12800][384] = xTr[12800][64] @ Aeff[384][64]^T + constv
// ---------------------------------------------------------------------------
__global__ __launch_bounds__(256) void k4_gemm(
    const float* __restrict__ xTr, const float* __restrict__ Aeff,
    const float* __restrict__ constv, float* __restrict__ xp)
{
  const int m0 = blockIdx.x*64, g0 = blockIdx.y*64;
  __shared__ float sX[64*68];
  __shared__ float sA[64*68];
  const int tid = threadIdx.x;
  const float4* xTr4 = (const float4*)xTr;
  const float4* A4   = (const float4*)Aeff;

  #pragma unroll
  for (int i=0;i<4;i++) {
    int f = tid + i*256;
    int row = f >> 4, kq = f & 15;
    float4 v = xTr4[(m0+row)*16 + kq];
    float vv[4] = {v.x,v.y,v.z,v.w};
    float4 w = A4[(g0+row)*16 + kq];
    float wv[4] = {w.x,w.y,w.z,w.w};
    #pragma unroll
    for (int q=0;q<4;q++) {
      sX[(kq*4+q)*68 + row] = vv[q];
      sA[(kq*4+q)*68 + row] = wv[q];
    }
  }
  __syncthreads();

  const int tm = tid & 15, tn = tid >> 4;
  float acc[4][4] = {};
  #pragma unroll 8
  for (int k=0;k<64;k++) {
    float4 a  = *(const float4*)&sX[k*68 + tm*4];
    float4 bb = *(const float4*)&sA[k*68 + tn*4];
    float av[4]={a.x,a.y,a.z,a.w}, bv[4]={bb.x,bb.y,bb.z,bb.w};
    #pragma unroll
    for (int i=0;i<4;i++)
      #pragma unroll
      for (int j=0;j<4;j++)
        acc[i][j] = fmaf(av[i], bv[j], acc[i][j]);
  }

  float cv[4];
  #pragma unroll
  for (int j=0;j<4;j++) cv[j] = constv[g0 + tn*4 + j];
  #pragma unroll
  for (int i=0;i<4;i++) {
    int mrow = m0 + tm*4 + i;
    #pragma unroll
    for (int j=0;j<4;j++)
      xp[mrow*384 + g0 + tn*4 + j] = acc[i][j] + cv[j];
  }
}

// ---------------------------------------------------------------------------
// K5: biGRU recurrence. 128 blocks = (b,dir); 256 threads (4 waves).
// R7 structure. KEY CHANGE: amdgpu_waves_per_eu(1,1) sets the backend
// scheduler's occupancy TARGET to 1 wave/EU (launch_bounds only raises the
// budget; the scheduler was still minimizing pressure toward max occupancy
// and sinking the loop-invariant weight loads into the loop -> VGPR=44 and
// ~200-300cyc of L2 wait per step in R7/R8). This launch is 512 waves on
// 1024 EUs (~0.5 waves/EU), so a 1-wave/EU allocation target costs nothing.
// ---------------------------------------------------------------------------
__global__ __launch_bounds__(256)
__attribute__((amdgpu_waves_per_eu(1, 1)))
void k5_gru(
    const float* __restrict__ xp,
    const float* __restrict__ Whh_f, const float* __restrict__ bhh_f,
    const float* __restrict__ Whh_b, const float* __restrict__ bhh_b,
    float* __restrict__ gru_out)
{
  const int bd = blockIdx.x;
  const int b = bd >> 1, dir = bd & 1;
  const int tid = threadIdx.x;
  const int w  = tid >> 6;              // wave 0..3
  const int l  = tid & 63;
  const int u  = l & 15;                // unit-in-wave
  const int s  = l >> 4;                // segment 0..3
  const int ug = w*16 + u;              // global hidden unit 0..63
  const float* Whh = dir ? Whh_b : Whh_f;
  const float* bhh = dir ? bhh_b : bhh_f;

  // resident weights: rows {ug, 64+ug, 128+ug}, cols 16s..16s+15
  f4 wr[4], wz[4], wn[4];
  #pragma unroll
  for (int j=0;j<4;j++){
    wr[j] = ((const f4*)(Whh + (size_t)(      ug)*64 + 16*s))[j];
    wz[j] = ((const f4*)(Whh + (size_t)( 64 + ug)*64 + 16*s))[j];
    wn[j] = ((const f4*)(Whh + (size_t)(128 + ug)*64 + 16*s))[j];
  }
  const float br_ = bhh[ug], bz_ = bhh[64+ug], bn_ = bhh[128+ug];

  __shared__ __align__(16) float hbuf[2][64];
  if (tid < 64) { hbuf[0][tid] = 0.f; hbuf[1][tid] = 0.f; }
  float hprev = 0.f;

  const int t0 = dir ? (Tt-1) : 0;
  const int tstep = dir ? -1 : 1;
  const float* xb = xp + (size_t)(b*Tt)*384 + dir*192 + ug;
  float* gout = gru_out + (size_t)(b*Tt)*128 + dir*64 + ug;

  float xrA = xb[(size_t)t0*384], xzA = xb[(size_t)t0*384+64], xnA = xb[(size_t)t0*384+128];
  const int t1 = t0 + tstep;
  float xrB = xb[(size_t)t1*384], xzB = xb[(size_t)t1*384+64], xnB = xb[(size_t)t1*384+128];
  __syncthreads();                       // hbuf init + first prefetch visible

  int t = t0;
  auto STEP = [&](float& xr, float& xz, float& xn, int rb){
    // consume this step's x-parts, then immediately issue the t+2 reload so
    // its latency overlaps the matvec/shuffles/gates below.
    const float cxr=xr, cxz=xz, cxn=xn;
    const int tpre = t + 2*tstep;
    if ((unsigned)tpre < (unsigned)Tt) {
      xr = xb[(size_t)tpre*384];
      xz = xb[(size_t)tpre*384+64];
      xn = xb[(size_t)tpre*384+128];
    }

    const f4* hp = (const f4*)&hbuf[rb][16*s];
    float ar=0.f, az=0.f, an=0.f;
    #pragma unroll
    for (int j=0;j<4;j++){
      f4 hv = hp[j];
      ar=fmaf(wr[j].x,hv.x,ar); ar=fmaf(wr[j].y,hv.y,ar);
      ar=fmaf(wr[j].z,hv.z,ar); ar=fmaf(wr[j].w,hv.w,ar);
      az=fmaf(wz[j].x,hv.x,az); az=fmaf(wz[j].y,hv.y,az);
      az=fmaf(wz[j].z,hv.z,az); az=fmaf(wz[j].w,hv.w,az);
      an=fmaf(wn[j].x,hv.x,an); an=fmaf(wn[j].y,hv.y,an);
      an=fmaf(wn[j].z,hv.z,an); an=fmaf(wn[j].w,hv.w,an);
    }
    // cross-segment butterfly: all 4 copies end with the full sums
    ar += __shfl_xor(ar,16,64); az += __shfl_xor(az,16,64); an += __shfl_xor(an,16,64);
    ar += __shfl_xor(ar,32,64); az += __shfl_xor(az,32,64); an += __shfl_xor(an,32,64);

    float r    = sigm(cxr + ar + br_);
    float z    = sigm(cxz + az + bz_);
    float nn2  = tanh_fast(cxn + r*(an + bn_));
    float hnew = (1.f - z)*nn2 + z*hprev;
    hprev = hnew;                            // identical on all 4 copies
    if (s == 0) {
      hbuf[rb^1][ug] = hnew;
      gout[(size_t)t*128] = hnew;
    }
    t += tstep;
    __syncthreads();                         // hnew visible for next step
  };

  for (int sp=0; sp<Tt; sp+=2) { STEP(xrA,xzA,xnA,0); STEP(xrB,xzB,xnB,1); }
}

// ---------------------------------------------------------------------------
// K6: attention pooling + classifier. One block per batch item.
// ---------------------------------------------------------------------------
__global__ __launch_bounds__(256) void k6_attn(
    const float* __restrict__ gru_out,
    const float* __restrict__ attn_W, const float* __restrict__ attn_b,
    const float* __restrict__ clf_W,  const float* __restrict__ clf_b,
    float* __restrict__ out)
{
  const int b = blockIdx.x, tid = threadIdx.x;
  __shared__ float s_s[Tt];
  __shared__ float red[256];
  __shared__ float aW[128], cW[128];
  if (tid < 128) { aW[tid]=attn_W[tid]; cW[tid]=clf_W[tid]; }
  __syncthreads();

  if (tid < Tt) {
    const float* row = gru_out + (b*Tt + tid)*128;
    float acc = 0.f;
    for (int j=0;j<128;j++) acc = fmaf(row[j], aW[j], acc);
    s_s[tid] = tanhf(acc + attn_b[0]);
  }
  __syncthreads();

  red[tid] = (tid < Tt) ? s_s[tid] : -1e30f;
  __syncthreads();
  for (int s2=128;s2;s2>>=1){ if(tid<s2) red[tid]=fmaxf(red[tid],red[tid+s2]); __syncthreads(); }
  float mx = red[0];
  __syncthreads();

  float e = 0.f;
  if (tid < Tt) { e = expf(s_s[tid]-mx); s_s[tid] = e; }
  red[tid] = e;
  __syncthreads();
  for (int s2=128;s2;s2>>=1){ if(tid<s2) red[tid]+=red[tid+s2]; __syncthreads(); }
  float total = red[0];
  __syncthreads();

  float p = 0.f;
  if (tid < 128) {
    float c = 0.f;
    for (int t=0;t<Tt;t++) c = fmaf(s_s[t], gru_out[(b*Tt+t)*128 + tid], c);
    p = (c/total)*cW[tid];
  }
  red[tid] = p;
  __syncthreads();
  for (int s2=128;s2;s2>>=1){ if(tid<s2) red[tid]+=red[tid+s2]; __syncthreads(); }
  if (tid==0) out[b] = sigm(red[0] + clf_b[0]);
}

// ---------------------------------------------------------------------------
extern "C" void kernel_launch(void* const* d_in, const int* in_sizes, int n_in,
                              void* d_out, int out_size, void* d_ws, size_t ws_size,
                              hipStream_t stream)
{
  const float* x      = (const float*)d_in[0];
  const int*   sp_ei  = (const int*)  d_in[1];
  const float* sp_ew  = (const float*)d_in[2];
  const int*   fn_ei  = (const int*)  d_in[3];
  const float* fn_ew  = (const float*)d_in[4];
  const float* Wcheb  = (const float*)d_in[5];
  const float* bcheb  = (const float*)d_in[6];
  const float* Wgcn   = (const float*)d_in[7];
  const float* bgcn   = (const float*)d_in[8];
  const float* Wih_f  = (const float*)d_in[9];
  const float* Whh_f  = (const float*)d_in[10];
  const float* bih_f  = (const float*)d_in[11];
  const float* bhh_f  = (const float*)d_in[12];
  const float* Wih_b  = (const float*)d_in[13];
  const float* Whh_b  = (const float*)d_in[14];
  const float* bih_b  = (const float*)d_in[15];
  const float* bhh_b  = (const float*)d_in[16];
  const float* attn_W = (const float*)d_in[17];
  const float* attn_b = (const float*)d_in[18];
  const float* clf_W  = (const float*)d_in[19];
  const float* clf_b  = (const float*)d_in[20];
  float* out = (float*)d_out;

  float* ws     = (float*)d_ws;
  float* Lg     = ws;                    // 4096
  float* L2g    = Lg   + 4096;           // 4096
  float* Gm     = L2g  + 4096;           // 4096
  float* Aeff   = Gm   + 4096;           // 384*64 = 24576
  float* constv = Aeff + 24576;          // 384 (+pad to 512)
  float* xTr    = constv + 512;          // 12800*64 = 819200
  float* xp     = xTr  + 819200;         // 12800*384 = 4915200
  float* gro    = xp   + 4915200;        // 12800*128 = 1638400

  hipLaunchKernelGGL(k1_graphs,    dim3(1),      dim3(256), 0, stream,
                     sp_ei, sp_ew, fn_ei, fn_ew, Lg, L2g, Gm);
  hipLaunchKernelGGL(k3_transpose, dim3(64),     dim3(256), 0, stream, x, xTr);
  hipLaunchKernelGGL(k2_aeff,      dim3(384),    dim3(64),  0, stream,
                     Wih_f, bih_f, Wih_b, bih_b, Wcheb, bcheb, Wgcn, bgcn,
                     Lg, L2g, Gm, Aeff, constv);
  hipLaunchKernelGGL(k4_gemm,      dim3(200, 6), dim3(256), 0, stream,
                     xTr, Aeff, constv, xp);
  hipLaunchKernelGGL(k5_gru,       dim3(128),    dim3(256), 0, stream,
                     xp, Whh_f, bhh_f, Whh_b, bhh_b, gro);
  hipLaunchKernelGGL(k6_attn,      dim3(64),     dim3(256), 0, stream,
                     gro, attn_W, attn_b, clf_W, clf_b, out);
}

// Round 10
// 155.593 us; speedup vs baseline: 1.3330x; 1.1008x over previous
//
#include <hip/hip_runtime.h>
#include <math.h>

#define Nn 64
#define Tt 200
#define Bb 64

__device__ __forceinline__ float sigm(float x){ return 1.0f/(1.0f+__expf(-x)); }
__device__ __forceinline__ float tanh_fast(float x){
  x = fminf(fmaxf(x, -15.f), 15.f);
  float e = __expf(-2.f*x);
  return (1.f - e)/(1.f + e);
}

typedef __attribute__((ext_vector_type(2))) _Float16 h2v;
typedef __attribute__((ext_vector_type(4))) float f4;

// fp16 dot2 with fp32 accumulate (v_dot2_f32_f16).
#if __has_builtin(__builtin_amdgcn_fdot2)
#define DOT2(w,hv,acc) __builtin_amdgcn_fdot2((w),(hv),(acc),false)
#else
#define DOT2(w,hv,acc) fmaf((float)(w)[0],(float)(hv)[0], fmaf((float)(w)[1],(float)(hv)[1],(acc)))
#endif

// ---------------------------------------------------------------------------
// K1: build graph operators. L = -S_cheb, L2 = 2*S@S - I, G = S_gcn (+diag).
// ---------------------------------------------------------------------------
__global__ __launch_bounds__(256) void k1_graphs(
    const int* __restrict__ sp_ei, const float* __restrict__ sp_ew,
    const int* __restrict__ fn_ei, const float* __restrict__ fn_ew,
    float* __restrict__ Lg, float* __restrict__ L2g, float* __restrict__ Gm)
{
  __shared__ float deg[Nn];
  __shared__ float dinv[Nn];
  __shared__ float S[64*68];            // padded stride 68
  const int tid = threadIdx.x;

  // ---- ChebConv operator (512 edges) ----
  if (tid < Nn) deg[tid] = 0.f;
  for (int i=tid;i<64*68;i+=256) S[i]=0.f;
  __syncthreads();
  for (int e=tid;e<512;e+=256) atomicAdd(&deg[sp_ei[e]], sp_ew[e]);   // deg over row
  __syncthreads();
  if (tid < Nn) dinv[tid] = (deg[tid] > 0.f) ? rsqrtf(deg[tid]) : 0.f;
  __syncthreads();
  for (int e=tid;e<512;e+=256) {
    int r = sp_ei[e], c = sp_ei[512+e];
    atomicAdd(&S[c*68 + r], dinv[r]*sp_ew[e]*dinv[c]);
  }
  __syncthreads();
  for (int i=tid;i<4096;i+=256) Lg[i] = -S[(i>>6)*68 + (i&63)];   // Ltil = -S
  {
    const int n = tid>>2, mb = (tid&3)*16;
    float a[16];
    #pragma unroll
    for (int q=0;q<16;q++) a[q]=0.f;
    for (int j=0;j<64;j++){
      float snj = S[n*68+j];
      const float4* rj = (const float4*)&S[j*68+mb];
      #pragma unroll
      for (int q=0;q<4;q++){
        float4 v = rj[q];
        a[q*4+0]=fmaf(snj,v.x,a[q*4+0]);
        a[q*4+1]=fmaf(snj,v.y,a[q*4+1]);
        a[q*4+2]=fmaf(snj,v.z,a[q*4+2]);
        a[q*4+3]=fmaf(snj,v.w,a[q*4+3]);
      }
    }
    #pragma unroll
    for (int q=0;q<16;q++){
      int m = mb+q;
      L2g[n*64+m] = 2.f*a[q] - (n==m ? 1.f : 0.f);
    }
  }
  __syncthreads();   // all reads of S done before reuse

  // ---- GCNConv operator (1024 edges) ----
  if (tid < Nn) deg[tid] = 0.f;
  for (int i=tid;i<64*68;i+=256) S[i]=0.f;
  __syncthreads();
  for (int e=tid;e<1024;e+=256) atomicAdd(&deg[fn_ei[1024+e]], fn_ew[e]);  // deg over col
  __syncthreads();
  if (tid < Nn) dinv[tid] = rsqrtf(deg[tid] + 1.f);
  __syncthreads();
  for (int e=tid;e<1024;e+=256) {
    int r = fn_ei[e], c = fn_ei[1024+e];
    atomicAdd(&S[c*68 + r], dinv[r]*fn_ew[e]*dinv[c]);
  }
  __syncthreads();
  if (tid < Nn) S[tid*68 + tid] += dinv[tid]*dinv[tid];     // + diag(1/deg)
  __syncthreads();
  for (int i=tid;i<4096;i+=256) Gm[i] = S[(i>>6)*68 + (i&63)];
}

// ---------------------------------------------------------------------------
// K2: fold Wih (+Wcheb/Wgcn/graph ops) into Aeff[384][64] and constv[384].
// ---------------------------------------------------------------------------
__global__ __launch_bounds__(64) void k2_aeff(
    const float* __restrict__ Wih_f, const float* __restrict__ bih_f,
    const float* __restrict__ Wih_b, const float* __restrict__ bih_b,
    const float* __restrict__ Wcheb, const float* __restrict__ bcheb,
    const float* __restrict__ Wgcn,  const float* __restrict__ bgcn,
    const float* __restrict__ Lg, const float* __restrict__ L2g,
    const float* __restrict__ Gm,
    float* __restrict__ Aeff, float* __restrict__ constv)
{
  const int g = blockIdx.x;                 // 0..383
  const int dir = (g >= 192) ? 1 : 0;
  const int grow = dir ? g - 192 : g;
  const float* Wih = dir ? Wih_b : Wih_f;
  const float* bih = dir ? bih_b : bih_f;

  __shared__ float wrow[64*129];
  __shared__ float arow[256];
  const int tid = threadIdx.x;              // 64 threads = 1 wave

  for (int i = tid; i < 8192; i += 64)
    wrow[(i>>7)*129 + (i&127)] = Wih[grow*8192 + i];
  __syncthreads();

  const int n = tid;
  float a0=0.f,a1=0.f,a2=0.f,a3=0.f,cp=0.f;
  for (int c=0;c<64;c++) {
    float w1 = wrow[n*129 + c];
    a0 = fmaf(w1, Wcheb[c],     a0);
    a1 = fmaf(w1, Wcheb[64+c],  a1);
    a2 = fmaf(w1, Wcheb[128+c], a2);
    cp = fmaf(w1, bcheb[c],     cp);
    float w2 = wrow[n*129 + 64 + c];
    a3 = fmaf(w2, Wgcn[c], a3);
    cp = fmaf(w2, bgcn[c], cp);
  }
  arow[n*4+0]=a0; arow[n*4+1]=a1; arow[n*4+2]=a2; arow[n*4+3]=a3;
  for (int off=32; off; off>>=1) cp += __shfl_down(cp, off, 64);
  if (tid==0) constv[g] = cp + bih[grow];
  __syncthreads();

  const int m = tid;
  float ae = arow[m*4+0];
  for (int nn2=0; nn2<64; nn2++) {
    ae = fmaf(arow[nn2*4+1], Lg [nn2*64+m], ae);
    ae = fmaf(arow[nn2*4+2], L2g[nn2*64+m], ae);
    ae = fmaf(arow[nn2*4+3], Gm [nn2*64+m], ae);
  }
  Aeff[g*64+m] = ae;
}

// ---------------------------------------------------------------------------
// K3: transpose x[B][N][T] -> xTr[B*T][N]
// ---------------------------------------------------------------------------
__global__ __launch_bounds__(256) void k3_transpose(
    const float* __restrict__ x, float* __restrict__ xTr)
{
  const int b = blockIdx.x;
  for (int idx = threadIdx.x; idx < Tt*Nn; idx += 256) {
    int t = idx >> 6, m = idx & 63;
    xTr[(b*Tt + t)*64 + m] = x[(b*64 + m)*Tt + t];
  }
}

// ---------------------------------------------------------------------------
// K4: xp[12800][384] = xTr[12800][64] @ Aeff[384][64]^T + constv
// ---------------------------------------------------------------------------
__global__ __launch_bounds__(256) void k4_gemm(
    const float* __restrict__ xTr, const float* __restrict__ Aeff,
    const float* __restrict__ constv, float* __restrict__ xp)
{
  const int m0 = blockIdx.x*64, g0 = blockIdx.y*64;
  __shared__ float sX[64*68];
  __shared__ float sA[64*68];
  const int tid = threadIdx.x;
  const float4* xTr4 = (const float4*)xTr;
  const float4* A4   = (const float4*)Aeff;

  #pragma unroll
  for (int i=0;i<4;i++) {
    int f = tid + i*256;
    int row = f >> 4, kq = f & 15;
    float4 v = xTr4[(m0+row)*16 + kq];
    float vv[4] = {v.x,v.y,v.z,v.w};
    float4 w = A4[(g0+row)*16 + kq];
    float wv[4] = {w.x,w.y,w.z,w.w};
    #pragma unroll
    for (int q=0;q<4;q++) {
      sX[(kq*4+q)*68 + row] = vv[q];
      sA[(kq*4+q)*68 + row] = wv[q];
    }
  }
  __syncthreads();

  const int tm = tid & 15, tn = tid >> 4;
  float acc[4][4] = {};
  #pragma unroll 8
  for (int k=0;k<64;k++) {
    float4 a  = *(const float4*)&sX[k*68 + tm*4];
    float4 bb = *(const float4*)&sA[k*68 + tn*4];
    float av[4]={a.x,a.y,a.z,a.w}, bv[4]={bb.x,bb.y,bb.z,bb.w};
    #pragma unroll
    for (int i=0;i<4;i++)
      #pragma unroll
      for (int j=0;j<4;j++)
        acc[i][j] = fmaf(av[i], bv[j], acc[i][j]);
  }

  float cv[4];
  #pragma unroll
  for (int j=0;j<4;j++) cv[j] = constv[g0 + tn*4 + j];
  #pragma unroll
  for (int i=0;i<4;i++) {
    int mrow = m0 + tm*4 + i;
    #pragma unroll
    for (int j=0;j<4;j++)
      xp[mrow*384 + g0 + tn*4 + j] = acc[i][j] + cv[j];
  }
}

// ---------------------------------------------------------------------------
// K5: biGRU recurrence, register-only. 128 blocks = (b,dir), ONE wave.
// Lane g owns hidden unit g; h stays in a VGPR. Broadcast via v_readlane of
// fp16-packed pairs (no LDS, no barriers, no cross-wave). Weights resident
// as fp16 pairs (96 VGPRs); matvec = 96 v_dot2_f32_f16 (fp32 accumulate).
// amdgpu_waves_per_eu(1,1): R9 proved this flips the backend scheduler from
// occupancy-minimizing (which remat'd these weights into the loop -> R6's
// 107us at VGPR=72) to latency-minimizing with full residency (VGPR=132).
// ---------------------------------------------------------------------------
__global__ __launch_bounds__(64)
__attribute__((amdgpu_waves_per_eu(1, 1)))
void k5_gru(
    const float* __restrict__ xp,
    const float* __restrict__ Whh_f, const float* __restrict__ bhh_f,
    const float* __restrict__ Whh_b, const float* __restrict__ bhh_b,
    float* __restrict__ gru_out)
{
  const int bd = blockIdx.x;
  const int b = bd >> 1, dir = bd & 1;
  const int g = threadIdx.x & 63;
  const float* Whh = dir ? Whh_b : Whh_f;
  const float* bhh = dir ? bhh_b : bhh_f;

  // resident fp16-packed weight rows (3 gate rows for this lane's unit)
  h2v wr[32], wz[32], wn[32];
  #pragma unroll
  for (int i=0;i<32;i++){
    float2 a = ((const float2*)(Whh + (size_t)g*64))[i];
    float2 bq= ((const float2*)(Whh + (size_t)(64+g)*64))[i];
    float2 c = ((const float2*)(Whh + (size_t)(128+g)*64))[i];
    wr[i] = h2v{(_Float16)a.x, (_Float16)a.y};
    wz[i] = h2v{(_Float16)bq.x,(_Float16)bq.y};
    wn[i] = h2v{(_Float16)c.x, (_Float16)c.y};
  }
  const float br_ = bhh[g], bz_ = bhh[64+g], bn_ = bhh[128+g];

  const int t0 = dir ? (Tt-1) : 0;
  const int tstep = dir ? -1 : 1;
  const float* xb = xp + (size_t)(b*Tt)*384 + dir*192 + g;
  float* gout = gru_out + (size_t)(b*Tt)*128 + dir*64 + g;

  float h = 0.f;
  float xrA = xb[(size_t)t0*384], xzA = xb[(size_t)t0*384+64], xnA = xb[(size_t)t0*384+128];
  const int t1 = t0 + tstep;
  float xrB = xb[(size_t)t1*384], xzB = xb[(size_t)t1*384+64], xnB = xb[(size_t)t1*384+128];

  int t = t0;
  auto STEP = [&](float& xr, float& xz, float& xn){
    // pack {h[2i], h[2i+1]} as fp16 pair (valid on even lanes; only even
    // lanes are readlane'd)
    float nb = __shfl_xor(h, 1, 64);
    h2v hp; hp[0] = (_Float16)h; hp[1] = (_Float16)nb;
    const int hpk = __builtin_bit_cast(int, hp);

    float ar0=0.f,ar1=0.f,az0=0.f,az1=0.f,an0=0.f,an1=0.f;
    #pragma unroll
    for (int i=0;i<32;i+=2){
      int p0 = __builtin_amdgcn_readlane(hpk, 2*i);
      int p1 = __builtin_amdgcn_readlane(hpk, 2*i+2);
      h2v h0 = __builtin_bit_cast(h2v, p0);
      h2v h1 = __builtin_bit_cast(h2v, p1);
      ar0 = DOT2(wr[i],  h0, ar0);  az0 = DOT2(wz[i],  h0, az0);  an0 = DOT2(wn[i],  h0, an0);
      ar1 = DOT2(wr[i+1],h1, ar1);  az1 = DOT2(wz[i+1],h1, az1);  an1 = DOT2(wn[i+1],h1, an1);
    }

    const float cxr = xr, cxz = xz, cxn = xn;
    const int tpre = t + 2*tstep;
    if ((unsigned)tpre < (unsigned)Tt) {   // depth-2 prefetch, reload after use
      xr = xb[(size_t)tpre*384];
      xz = xb[(size_t)tpre*384+64];
      xn = xb[(size_t)tpre*384+128];
    }

    float r   = sigm(cxr + (ar0+ar1) + br_);
    float z   = sigm(cxz + (az0+az1) + bz_);
    float nn2 = tanh_fast(cxn + r*((an0+an1) + bn_));
    float hnew = (1.f - z)*nn2 + z*h;
    h = hnew;
    gout[(size_t)t*128] = hnew;
    t += tstep;
  };

  for (int sp=0; sp<Tt; sp+=2) { STEP(xrA,xzA,xnA); STEP(xrB,xzB,xnB); }
}

// ---------------------------------------------------------------------------
// K6: attention pooling + classifier. One block per batch item.
// ---------------------------------------------------------------------------
__global__ __launch_bounds__(256) void k6_attn(
    const float* __restrict__ gru_out,
    const float* __restrict__ attn_W, const float* __restrict__ attn_b,
    const float* __restrict__ clf_W,  const float* __restrict__ clf_b,
    float* __restrict__ out)
{
  const int b = blockIdx.x, tid = threadIdx.x;
  __shared__ float s_s[Tt];
  __shared__ float red[256];
  __shared__ float aW[128], cW[128];
  if (tid < 128) { aW[tid]=attn_W[tid]; cW[tid]=clf_W[tid]; }
  __syncthreads();

  if (tid < Tt) {
    const float* row = gru_out + (b*Tt + tid)*128;
    float acc = 0.f;
    for (int j=0;j<128;j++) acc = fmaf(row[j], aW[j], acc);
    s_s[tid] = tanhf(acc + attn_b[0]);
  }
  __syncthreads();

  red[tid] = (tid < Tt) ? s_s[tid] : -1e30f;
  __syncthreads();
  for (int s2=128;s2;s2>>=1){ if(tid<s2) red[tid]=fmaxf(red[tid],red[tid+s2]); __syncthreads(); }
  float mx = red[0];
  __syncthreads();

  float e = 0.f;
  if (tid < Tt) { e = expf(s_s[tid]-mx); s_s[tid] = e; }
  red[tid] = e;
  __syncthreads();
  for (int s2=128;s2;s2>>=1){ if(tid<s2) red[tid]+=red[tid+s2]; __syncthreads(); }
  float total = red[0];
  __syncthreads();

  float p = 0.f;
  if (tid < 128) {
    float c = 0.f;
    for (int t=0;t<Tt;t++) c = fmaf(s_s[t], gru_out[(b*Tt+t)*128 + tid], c);
    p = (c/total)*cW[tid];
  }
  red[tid] = p;
  __syncthreads();
  for (int s2=128;s2;s2>>=1){ if(tid<s2) red[tid]+=red[tid+s2]; __syncthreads(); }
  if (tid==0) out[b] = sigm(red[0] + clf_b[0]);
}

// ---------------------------------------------------------------------------
extern "C" void kernel_launch(void* const* d_in, const int* in_sizes, int n_in,
                              void* d_out, int out_size, void* d_ws, size_t ws_size,
                              hipStream_t stream)
{
  const float* x      = (const float*)d_in[0];
  const int*   sp_ei  = (const int*)  d_in[1];
  const float* sp_ew  = (const float*)d_in[2];
  const int*   fn_ei  = (const int*)  d_in[3];
  const float* fn_ew  = (const float*)d_in[4];
  const float* Wcheb  = (const float*)d_in[5];
  const float* bcheb  = (const float*)d_in[6];
  const float* Wgcn   = (const float*)d_in[7];
  const float* bgcn   = (const float*)d_in[8];
  const float* Wih_f  = (const float*)d_in[9];
  const float* Whh_f  = (const float*)d_in[10];
  const float* bih_f  = (const float*)d_in[11];
  const float* bhh_f  = (const float*)d_in[12];
  const float* Wih_b  = (const float*)d_in[13];
  const float* Whh_b  = (const float*)d_in[14];
  const float* bih_b  = (const float*)d_in[15];
  const float* bhh_b  = (const float*)d_in[16];
  const float* attn_W = (const float*)d_in[17];
  const float* attn_b = (const float*)d_in[18];
  const float* clf_W  = (const float*)d_in[19];
  const float* clf_b  = (const float*)d_in[20];
  float* out = (float*)d_out;

  float* ws     = (float*)d_ws;
  float* Lg     = ws;                    // 4096
  float* L2g    = Lg   + 4096;           // 4096
  float* Gm     = L2g  + 4096;           // 4096
  float* Aeff   = Gm   + 4096;           // 384*64 = 24576
  float* constv = Aeff + 24576;          // 384 (+pad to 512)
  float* xTr    = constv + 512;          // 12800*64 = 819200
  float* xp     = xTr  + 819200;         // 12800*384 = 4915200
  float* gro    = xp   + 4915200;        // 12800*128 = 1638400

  hipLaunchKernelGGL(k1_graphs,    dim3(1),      dim3(256), 0, stream,
                     sp_ei, sp_ew, fn_ei, fn_ew, Lg, L2g, Gm);
  hipLaunchKernelGGL(k3_transpose, dim3(64),     dim3(256), 0, stream, x, xTr);
  hipLaunchKernelGGL(k2_aeff,      dim3(384),    dim3(64),  0, stream,
                     Wih_f, bih_f, Wih_b, bih_b, Wcheb, bcheb, Wgcn, bgcn,
                     Lg, L2g, Gm, Aeff, constv);
  hipLaunchKernelGGL(k4_gemm,      dim3(200, 6), dim3(256), 0, stream,
                     xTr, Aeff, constv, xp);
  hipLaunchKernelGGL(k5_gru,       dim3(128),    dim3(64),  0, stream,
                     xp, Whh_f, bhh_f, Whh_b, bhh_b, gro);
  hipLaunchKernelGGL(k6_attn,      dim3(64),     dim3(256), 0, stream,
                     gro, attn_W, attn_b, clf_W, clf_b, out);
}

// Round 11
// 145.263 us; speedup vs baseline: 1.4278x; 1.0711x over previous
//
#include <hip/hip_runtime.h>
#include <math.h>

#define Nn 64
#define Tt 200
#define Bb 64

__device__ __forceinline__ float sigm(float x){ return 1.0f/(1.0f+__expf(-x)); }
__device__ __forceinline__ float tanh_fast(float x){
  x = fminf(fmaxf(x, -15.f), 15.f);
  float e = __expf(-2.f*x);
  return (1.f - e)/(1.f + e);
}

typedef __attribute__((ext_vector_type(2))) _Float16 h2v;
typedef __attribute__((ext_vector_type(4))) float f4;

// fp16 dot2 with fp32 accumulate (v_dot2_f32_f16).
#if __has_builtin(__builtin_amdgcn_fdot2)
#define DOT2(w,hv,acc) __builtin_amdgcn_fdot2((w),(hv),(acc),false)
#else
#define DOT2(w,hv,acc) fmaf((float)(w)[0],(float)(hv)[0], fmaf((float)(w)[1],(float)(hv)[1],(acc)))
#endif

// ---------------------------------------------------------------------------
// K1: build graph operators. L = -S_cheb, L2 = 2*S@S - I, G = S_gcn (+diag).
// ---------------------------------------------------------------------------
__global__ __launch_bounds__(256) void k1_graphs(
    const int* __restrict__ sp_ei, const float* __restrict__ sp_ew,
    const int* __restrict__ fn_ei, const float* __restrict__ fn_ew,
    float* __restrict__ Lg, float* __restrict__ L2g, float* __restrict__ Gm)
{
  __shared__ float deg[Nn];
  __shared__ float dinv[Nn];
  __shared__ float S[64*68];            // padded stride 68
  const int tid = threadIdx.x;

  // ---- ChebConv operator (512 edges) ----
  if (tid < Nn) deg[tid] = 0.f;
  for (int i=tid;i<64*68;i+=256) S[i]=0.f;
  __syncthreads();
  for (int e=tid;e<512;e+=256) atomicAdd(&deg[sp_ei[e]], sp_ew[e]);   // deg over row
  __syncthreads();
  if (tid < Nn) dinv[tid] = (deg[tid] > 0.f) ? rsqrtf(deg[tid]) : 0.f;
  __syncthreads();
  for (int e=tid;e<512;e+=256) {
    int r = sp_ei[e], c = sp_ei[512+e];
    atomicAdd(&S[c*68 + r], dinv[r]*sp_ew[e]*dinv[c]);
  }
  __syncthreads();
  for (int i=tid;i<4096;i+=256) Lg[i] = -S[(i>>6)*68 + (i&63)];   // Ltil = -S
  {
    const int n = tid>>2, mb = (tid&3)*16;
    float a[16];
    #pragma unroll
    for (int q=0;q<16;q++) a[q]=0.f;
    for (int j=0;j<64;j++){
      float snj = S[n*68+j];
      const float4* rj = (const float4*)&S[j*68+mb];
      #pragma unroll
      for (int q=0;q<4;q++){
        float4 v = rj[q];
        a[q*4+0]=fmaf(snj,v.x,a[q*4+0]);
        a[q*4+1]=fmaf(snj,v.y,a[q*4+1]);
        a[q*4+2]=fmaf(snj,v.z,a[q*4+2]);
        a[q*4+3]=fmaf(snj,v.w,a[q*4+3]);
      }
    }
    #pragma unroll
    for (int q=0;q<16;q++){
      int m = mb+q;
      L2g[n*64+m] = 2.f*a[q] - (n==m ? 1.f : 0.f);
    }
  }
  __syncthreads();   // all reads of S done before reuse

  // ---- GCNConv operator (1024 edges) ----
  if (tid < Nn) deg[tid] = 0.f;
  for (int i=tid;i<64*68;i+=256) S[i]=0.f;
  __syncthreads();
  for (int e=tid;e<1024;e+=256) atomicAdd(&deg[fn_ei[1024+e]], fn_ew[e]);  // deg over col
  __syncthreads();
  if (tid < Nn) dinv[tid] = rsqrtf(deg[tid] + 1.f);
  __syncthreads();
  for (int e=tid;e<1024;e+=256) {
    int r = fn_ei[e], c = fn_ei[1024+e];
    atomicAdd(&S[c*68 + r], dinv[r]*fn_ew[e]*dinv[c]);
  }
  __syncthreads();
  if (tid < Nn) S[tid*68 + tid] += dinv[tid]*dinv[tid];     // + diag(1/deg)
  __syncthreads();
  for (int i=tid;i<4096;i+=256) Gm[i] = S[(i>>6)*68 + (i&63)];
}

// ---------------------------------------------------------------------------
// K2: fold Wih (+Wcheb/Wgcn/graph ops) into Aeff[384][64] and constv[384].
// ---------------------------------------------------------------------------
__global__ __launch_bounds__(64) void k2_aeff(
    const float* __restrict__ Wih_f, const float* __restrict__ bih_f,
    const float* __restrict__ Wih_b, const float* __restrict__ bih_b,
    const float* __restrict__ Wcheb, const float* __restrict__ bcheb,
    const float* __restrict__ Wgcn,  const float* __restrict__ bgcn,
    const float* __restrict__ Lg, const float* __restrict__ L2g,
    const float* __restrict__ Gm,
    float* __restrict__ Aeff, float* __restrict__ constv)
{
  const int g = blockIdx.x;                 // 0..383
  const int dir = (g >= 192) ? 1 : 0;
  const int grow = dir ? g - 192 : g;
  const float* Wih = dir ? Wih_b : Wih_f;
  const float* bih = dir ? bih_b : bih_f;

  __shared__ float wrow[64*129];
  __shared__ float arow[256];
  const int tid = threadIdx.x;              // 64 threads = 1 wave

  for (int i = tid; i < 8192; i += 64)
    wrow[(i>>7)*129 + (i&127)] = Wih[grow*8192 + i];
  __syncthreads();

  const int n = tid;
  float a0=0.f,a1=0.f,a2=0.f,a3=0.f,cp=0.f;
  for (int c=0;c<64;c++) {
    float w1 = wrow[n*129 + c];
    a0 = fmaf(w1, Wcheb[c],     a0);
    a1 = fmaf(w1, Wcheb[64+c],  a1);
    a2 = fmaf(w1, Wcheb[128+c], a2);
    cp = fmaf(w1, bcheb[c],     cp);
    float w2 = wrow[n*129 + 64 + c];
    a3 = fmaf(w2, Wgcn[c], a3);
    cp = fmaf(w2, bgcn[c], cp);
  }
  arow[n*4+0]=a0; arow[n*4+1]=a1; arow[n*4+2]=a2; arow[n*4+3]=a3;
  for (int off=32; off; off>>=1) cp += __shfl_down(cp, off, 64);
  if (tid==0) constv[g] = cp + bih[grow];
  __syncthreads();

  const int m = tid;
  float ae = arow[m*4+0];
  for (int nn2=0; nn2<64; nn2++) {
    ae = fmaf(arow[nn2*4+1], Lg [nn2*64+m], ae);
    ae = fmaf(arow[nn2*4+2], L2g[nn2*64+m], ae);
    ae = fmaf(arow[nn2*4+3], Gm [nn2*64+m], ae);
  }
  Aeff[g*64+m] = ae;
}

// ---------------------------------------------------------------------------
// K3: transpose x[B][N][T] -> xTr[B*T][N]
// ---------------------------------------------------------------------------
__global__ __launch_bounds__(256) void k3_transpose(
    const float* __restrict__ x, float* __restrict__ xTr)
{
  const int b = blockIdx.x;
  for (int idx = threadIdx.x; idx < Tt*Nn; idx += 256) {
    int t = idx >> 6, m = idx & 63;
    xTr[(b*Tt + t)*64 + m] = x[(b*64 + m)*Tt + t];
  }
}

// ---------------------------------------------------------------------------
// K4: xp[12800][384] = xTr[12800][64] @ Aeff[384][64]^T + constv
// ---------------------------------------------------------------------------
__global__ __launch_bounds__(256) void k4_gemm(
    const float* __restrict__ xTr, const float* __restrict__ Aeff,
    const float* __restrict__ constv, float* __restrict__ xp)
{
  const int m0 = blockIdx.x*64, g0 = blockIdx.y*64;
  __shared__ float sX[64*68];
  __shared__ float sA[64*68];
  const int tid = threadIdx.x;
  const float4* xTr4 = (const float4*)xTr;
  const float4* A4   = (const float4*)Aeff;

  #pragma unroll
  for (int i=0;i<4;i++) {
    int f = tid + i*256;
    int row = f >> 4, kq = f & 15;
    float4 v = xTr4[(m0+row)*16 + kq];
    float vv[4] = {v.x,v.y,v.z,v.w};
    float4 w = A4[(g0+row)*16 + kq];
    float wv[4] = {w.x,w.y,w.z,w.w};
    #pragma unroll
    for (int q=0;q<4;q++) {
      sX[(kq*4+q)*68 + row] = vv[q];
      sA[(kq*4+q)*68 + row] = wv[q];
    }
  }
  __syncthreads();

  const int tm = tid & 15, tn = tid >> 4;
  float acc[4][4] = {};
  #pragma unroll 8
  for (int k=0;k<64;k++) {
    float4 a  = *(const float4*)&sX[k*68 + tm*4];
    float4 bb = *(const float4*)&sA[k*68 + tn*4];
    float av[4]={a.x,a.y,a.z,a.w}, bv[4]={bb.x,bb.y,bb.z,bb.w};
    #pragma unroll
    for (int i=0;i<4;i++)
      #pragma unroll
      for (int j=0;j<4;j++)
        acc[i][j] = fmaf(av[i], bv[j], acc[i][j]);
  }

  float cv[4];
  #pragma unroll
  for (int j=0;j<4;j++) cv[j] = constv[g0 + tn*4 + j];
  #pragma unroll
  for (int i=0;i<4;i++) {
    int mrow = m0 + tm*4 + i;
    #pragma unroll
    for (int j=0;j<4;j++)
      xp[mrow*384 + g0 + tn*4 + j] = acc[i][j] + cv[j];
  }
}

// ---------------------------------------------------------------------------
// K5: biGRU recurrence, single wave per (b,dir). Lane g owns hidden unit g.
// Broadcast via LDS: lane writes its h as fp16 (ds_write_b16, 2 lanes/bank =
// conflict-free), then ALL lanes re-read the packed 128B h vector with 8
// broadcast ds_read_b128 into h2v registers. This removes R10's 32 v_readlane
// (VALU->SGPR hazard wait-states) and the ds_bpermute shfl from the critical
// path. No barriers (single wave; intra-wave lgkmcnt ordering).
// Weights resident as fp16 pairs (96 VGPRs; waves_per_eu(1,1) per R9/R10).
// ---------------------------------------------------------------------------
__global__ __launch_bounds__(64)
__attribute__((amdgpu_waves_per_eu(1, 1)))
void k5_gru(
    const float* __restrict__ xp,
    const float* __restrict__ Whh_f, const float* __restrict__ bhh_f,
    const float* __restrict__ Whh_b, const float* __restrict__ bhh_b,
    float* __restrict__ gru_out)
{
  const int bd = blockIdx.x;
  const int b = bd >> 1, dir = bd & 1;
  const int g = threadIdx.x & 63;
  const float* Whh = dir ? Whh_b : Whh_f;
  const float* bhh = dir ? bhh_b : bhh_f;

  // resident fp16-packed weight rows (3 gate rows for this lane's unit)
  h2v wr[32], wz[32], wn[32];
  #pragma unroll
  for (int i=0;i<32;i++){
    float2 a = ((const float2*)(Whh + (size_t)g*64))[i];
    float2 bq= ((const float2*)(Whh + (size_t)(64+g)*64))[i];
    float2 c = ((const float2*)(Whh + (size_t)(128+g)*64))[i];
    wr[i] = h2v{(_Float16)a.x, (_Float16)a.y};
    wz[i] = h2v{(_Float16)bq.x,(_Float16)bq.y};
    wn[i] = h2v{(_Float16)c.x, (_Float16)c.y};
  }
  const float br_ = bhh[g], bz_ = bhh[64+g], bn_ = bhh[128+g];

  __shared__ __align__(16) _Float16 hsh[64];   // packed fp16 h vector (128 B)
  hsh[g] = (_Float16)0.f;                      // initial h = 0

  const int t0 = dir ? (Tt-1) : 0;
  const int tstep = dir ? -1 : 1;
  const float* xb = xp + (size_t)(b*Tt)*384 + dir*192 + g;
  float* gout = gru_out + (size_t)(b*Tt)*128 + dir*64 + g;

  float h = 0.f;
  float xrA = xb[(size_t)t0*384], xzA = xb[(size_t)t0*384+64], xnA = xb[(size_t)t0*384+128];
  const int t1 = t0 + tstep;
  float xrB = xb[(size_t)t1*384], xzB = xb[(size_t)t1*384+64], xnB = xb[(size_t)t1*384+128];

  int t = t0;
  auto STEP = [&](float& xr, float& xz, float& xn){
    // broadcast-read the full packed h vector: 8x ds_read_b128, conflict-free
    h2v hv[32];
    {
      const uint4* hp4 = (const uint4*)hsh;
      #pragma unroll
      for (int q=0;q<8;q++){
        union { uint4 v; h2v p[4]; } uu;
        uu.v = hp4[q];
        hv[q*4+0]=uu.p[0]; hv[q*4+1]=uu.p[1]; hv[q*4+2]=uu.p[2]; hv[q*4+3]=uu.p[3];
      }
    }

    const float cxr = xr, cxz = xz, cxn = xn;
    const int tpre = t + 2*tstep;
    if ((unsigned)tpre < (unsigned)Tt) {   // depth-2 prefetch, reload after use
      xr = xb[(size_t)tpre*384];
      xz = xb[(size_t)tpre*384+64];
      xn = xb[(size_t)tpre*384+128];
    }

    float ar0=0.f,ar1=0.f,az0=0.f,az1=0.f,an0=0.f,an1=0.f;
    #pragma unroll
    for (int i=0;i<32;i+=2){
      ar0 = DOT2(wr[i],  hv[i],  ar0);  az0 = DOT2(wz[i],  hv[i],  az0);  an0 = DOT2(wn[i],  hv[i],  an0);
      ar1 = DOT2(wr[i+1],hv[i+1],ar1);  az1 = DOT2(wz[i+1],hv[i+1],az1);  an1 = DOT2(wn[i+1],hv[i+1],an1);
    }

    float r   = sigm(cxr + (ar0+ar1) + br_);
    float z   = sigm(cxz + (az0+az1) + bz_);
    float nn2 = tanh_fast(cxn + r*((an0+an1) + bn_));
    float hnew = (1.f - z)*nn2 + z*h;
    h = hnew;
    hsh[g] = (_Float16)hnew;               // ds_write_b16 for next step
    gout[(size_t)t*128] = hnew;
    t += tstep;
  };

  for (int sp=0; sp<Tt; sp+=2) { STEP(xrA,xzA,xnA); STEP(xrB,xzB,xnB); }
}

// ---------------------------------------------------------------------------
// K6: attention pooling + classifier. One block per batch item.
// ---------------------------------------------------------------------------
__global__ __launch_bounds__(256) void k6_attn(
    const float* __restrict__ gru_out,
    const float* __restrict__ attn_W, const float* __restrict__ attn_b,
    const float* __restrict__ clf_W,  const float* __restrict__ clf_b,
    float* __restrict__ out)
{
  const int b = blockIdx.x, tid = threadIdx.x;
  __shared__ float s_s[Tt];
  __shared__ float red[256];
  __shared__ float aW[128], cW[128];
  if (tid < 128) { aW[tid]=attn_W[tid]; cW[tid]=clf_W[tid]; }
  __syncthreads();

  if (tid < Tt) {
    const float* row = gru_out + (b*Tt + tid)*128;
    float acc = 0.f;
    for (int j=0;j<128;j++) acc = fmaf(row[j], aW[j], acc);
    s_s[tid] = tanhf(acc + attn_b[0]);
  }
  __syncthreads();

  red[tid] = (tid < Tt) ? s_s[tid] : -1e30f;
  __syncthreads();
  for (int s2=128;s2;s2>>=1){ if(tid<s2) red[tid]=fmaxf(red[tid],red[tid+s2]); __syncthreads(); }
  float mx = red[0];
  __syncthreads();

  float e = 0.f;
  if (tid < Tt) { e = expf(s_s[tid]-mx); s_s[tid] = e; }
  red[tid] = e;
  __syncthreads();
  for (int s2=128;s2;s2>>=1){ if(tid<s2) red[tid]+=red[tid+s2]; __syncthreads(); }
  float total = red[0];
  __syncthreads();

  float p = 0.f;
  if (tid < 128) {
    float c = 0.f;
    for (int t=0;t<Tt;t++) c = fmaf(s_s[t], gru_out[(b*Tt+t)*128 + tid], c);
    p = (c/total)*cW[tid];
  }
  red[tid] = p;
  __syncthreads();
  for (int s2=128;s2;s2>>=1){ if(tid<s2) red[tid]+=red[tid+s2]; __syncthreads(); }
  if (tid==0) out[b] = sigm(red[0] + clf_b[0]);
}

// ---------------------------------------------------------------------------
extern "C" void kernel_launch(void* const* d_in, const int* in_sizes, int n_in,
                              void* d_out, int out_size, void* d_ws, size_t ws_size,
                              hipStream_t stream)
{
  const float* x      = (const float*)d_in[0];
  const int*   sp_ei  = (const int*)  d_in[1];
  const float* sp_ew  = (const float*)d_in[2];
  const int*   fn_ei  = (const int*)  d_in[3];
  const float* fn_ew  = (const float*)d_in[4];
  const float* Wcheb  = (const float*)d_in[5];
  const float* bcheb  = (const float*)d_in[6];
  const float* Wgcn   = (const float*)d_in[7];
  const float* bgcn   = (const float*)d_in[8];
  const float* Wih_f  = (const float*)d_in[9];
  const float* Whh_f  = (const float*)d_in[10];
  const float* bih_f  = (const float*)d_in[11];
  const float* bhh_f  = (const float*)d_in[12];
  const float* Wih_b  = (const float*)d_in[13];
  const float* Whh_b  = (const float*)d_in[14];
  const float* bih_b  = (const float*)d_in[15];
  const float* bhh_b  = (const float*)d_in[16];
  const float* attn_W = (const float*)d_in[17];
  const float* attn_b = (const float*)d_in[18];
  const float* clf_W  = (const float*)d_in[19];
  const float* clf_b  = (const float*)d_in[20];
  float* out = (float*)d_out;

  float* ws     = (float*)d_ws;
  float* Lg     = ws;                    // 4096
  float* L2g    = Lg   + 4096;           // 4096
  float* Gm     = L2g  + 4096;           // 4096
  float* Aeff   = Gm   + 4096;           // 384*64 = 24576
  float* constv = Aeff + 24576;          // 384 (+pad to 512)
  float* xTr    = constv + 512;          // 12800*64 = 819200
  float* xp     = xTr  + 819200;         // 12800*384 = 4915200
  float* gro    = xp   + 4915200;        // 12800*128 = 1638400

  hipLaunchKernelGGL(k1_graphs,    dim3(1),      dim3(256), 0, stream,
                     sp_ei, sp_ew, fn_ei, fn_ew, Lg, L2g, Gm);
  hipLaunchKernelGGL(k3_transpose, dim3(64),     dim3(256), 0, stream, x, xTr);
  hipLaunchKernelGGL(k2_aeff,      dim3(384),    dim3(64),  0, stream,
                     Wih_f, bih_f, Wih_b, bih_b, Wcheb, bcheb, Wgcn, bgcn,
                     Lg, L2g, Gm, Aeff, constv);
  hipLaunchKernelGGL(k4_gemm,      dim3(200, 6), dim3(256), 0, stream,
                     xTr, Aeff, constv, xp);
  hipLaunchKernelGGL(k5_gru,       dim3(128),    dim3(64),  0, stream,
                     xp, Whh_f, bhh_f, Whh_b, bhh_b, gro);
  hipLaunchKernelGGL(k6_attn,      dim3(64),     dim3(256), 0, stream,
                     gro, attn_W, attn_b, clf_W, clf_b, out);
}

// Round 12
// 136.860 us; speedup vs baseline: 1.5155x; 1.0614x over previous
//
#include <hip/hip_runtime.h>
#include <math.h>

#define Nn 64
#define Tt 200
#define Bb 64

__device__ __forceinline__ float sigm(float x){ return 1.0f/(1.0f+__expf(-x)); }
__device__ __forceinline__ float tanh_fast(float x){
  x = fminf(fmaxf(x, -15.f), 15.f);
  float e = __expf(-2.f*x);
  return (1.f - e)/(1.f + e);
}

typedef __attribute__((ext_vector_type(2))) _Float16 h2v;
typedef __attribute__((ext_vector_type(4))) float f4;

// fp16 dot2 with fp32 accumulate (v_dot2_f32_f16).
#if __has_builtin(__builtin_amdgcn_fdot2)
#define DOT2(w,hv,acc) __builtin_amdgcn_fdot2((w),(hv),(acc),false)
#else
#define DOT2(w,hv,acc) fmaf((float)(w)[0],(float)(hv)[0], fmaf((float)(w)[1],(float)(hv)[1],(acc)))
#endif

// ---------------------------------------------------------------------------
// K1: build graph operators. L = -S_cheb, L2 = 2*S@S - I, G = S_gcn (+diag).
// ---------------------------------------------------------------------------
__global__ __launch_bounds__(256) void k1_graphs(
    const int* __restrict__ sp_ei, const float* __restrict__ sp_ew,
    const int* __restrict__ fn_ei, const float* __restrict__ fn_ew,
    float* __restrict__ Lg, float* __restrict__ L2g, float* __restrict__ Gm)
{
  __shared__ float deg[Nn];
  __shared__ float dinv[Nn];
  __shared__ float S[64*68];            // padded stride 68
  const int tid = threadIdx.x;

  // ---- ChebConv operator (512 edges) ----
  if (tid < Nn) deg[tid] = 0.f;
  for (int i=tid;i<64*68;i+=256) S[i]=0.f;
  __syncthreads();
  for (int e=tid;e<512;e+=256) atomicAdd(&deg[sp_ei[e]], sp_ew[e]);   // deg over row
  __syncthreads();
  if (tid < Nn) dinv[tid] = (deg[tid] > 0.f) ? rsqrtf(deg[tid]) : 0.f;
  __syncthreads();
  for (int e=tid;e<512;e+=256) {
    int r = sp_ei[e], c = sp_ei[512+e];
    atomicAdd(&S[c*68 + r], dinv[r]*sp_ew[e]*dinv[c]);
  }
  __syncthreads();
  for (int i=tid;i<4096;i+=256) Lg[i] = -S[(i>>6)*68 + (i&63)];   // Ltil = -S
  {
    const int n = tid>>2, mb = (tid&3)*16;
    float a[16];
    #pragma unroll
    for (int q=0;q<16;q++) a[q]=0.f;
    for (int j=0;j<64;j++){
      float snj = S[n*68+j];
      const float4* rj = (const float4*)&S[j*68+mb];
      #pragma unroll
      for (int q=0;q<4;q++){
        float4 v = rj[q];
        a[q*4+0]=fmaf(snj,v.x,a[q*4+0]);
        a[q*4+1]=fmaf(snj,v.y,a[q*4+1]);
        a[q*4+2]=fmaf(snj,v.z,a[q*4+2]);
        a[q*4+3]=fmaf(snj,v.w,a[q*4+3]);
      }
    }
    #pragma unroll
    for (int q=0;q<16;q++){
      int m = mb+q;
      L2g[n*64+m] = 2.f*a[q] - (n==m ? 1.f : 0.f);
    }
  }
  __syncthreads();   // all reads of S done before reuse

  // ---- GCNConv operator (1024 edges) ----
  if (tid < Nn) deg[tid] = 0.f;
  for (int i=tid;i<64*68;i+=256) S[i]=0.f;
  __syncthreads();
  for (int e=tid;e<1024;e+=256) atomicAdd(&deg[fn_ei[1024+e]], fn_ew[e]);  // deg over col
  __syncthreads();
  if (tid < Nn) dinv[tid] = rsqrtf(deg[tid] + 1.f);
  __syncthreads();
  for (int e=tid;e<1024;e+=256) {
    int r = fn_ei[e], c = fn_ei[1024+e];
    atomicAdd(&S[c*68 + r], dinv[r]*fn_ew[e]*dinv[c]);
  }
  __syncthreads();
  if (tid < Nn) S[tid*68 + tid] += dinv[tid]*dinv[tid];     // + diag(1/deg)
  __syncthreads();
  for (int i=tid;i<4096;i+=256) Gm[i] = S[(i>>6)*68 + (i&63)];
}

// ---------------------------------------------------------------------------
// K2: fold Wih (+Wcheb/Wgcn/graph ops) into Aeff[384][64] and constv[384].
// ---------------------------------------------------------------------------
__global__ __launch_bounds__(64) void k2_aeff(
    const float* __restrict__ Wih_f, const float* __restrict__ bih_f,
    const float* __restrict__ Wih_b, const float* __restrict__ bih_b,
    const float* __restrict__ Wcheb, const float* __restrict__ bcheb,
    const float* __restrict__ Wgcn,  const float* __restrict__ bgcn,
    const float* __restrict__ Lg, const float* __restrict__ L2g,
    const float* __restrict__ Gm,
    float* __restrict__ Aeff, float* __restrict__ constv)
{
  const int g = blockIdx.x;                 // 0..383
  const int dir = (g >= 192) ? 1 : 0;
  const int grow = dir ? g - 192 : g;
  const float* Wih = dir ? Wih_b : Wih_f;
  const float* bih = dir ? bih_b : bih_f;

  __shared__ float wrow[64*129];
  __shared__ float arow[256];
  const int tid = threadIdx.x;              // 64 threads = 1 wave

  for (int i = tid; i < 8192; i += 64)
    wrow[(i>>7)*129 + (i&127)] = Wih[grow*8192 + i];
  __syncthreads();

  const int n = tid;
  float a0=0.f,a1=0.f,a2=0.f,a3=0.f,cp=0.f;
  for (int c=0;c<64;c++) {
    float w1 = wrow[n*129 + c];
    a0 = fmaf(w1, Wcheb[c],     a0);
    a1 = fmaf(w1, Wcheb[64+c],  a1);
    a2 = fmaf(w1, Wcheb[128+c], a2);
    cp = fmaf(w1, bcheb[c],     cp);
    float w2 = wrow[n*129 + 64 + c];
    a3 = fmaf(w2, Wgcn[c], a3);
    cp = fmaf(w2, bgcn[c], cp);
  }
  arow[n*4+0]=a0; arow[n*4+1]=a1; arow[n*4+2]=a2; arow[n*4+3]=a3;
  for (int off=32; off; off>>=1) cp += __shfl_down(cp, off, 64);
  if (tid==0) constv[g] = cp + bih[grow];
  __syncthreads();

  const int m = tid;
  float ae = arow[m*4+0];
  for (int nn2=0; nn2<64; nn2++) {
    ae = fmaf(arow[nn2*4+1], Lg [nn2*64+m], ae);
    ae = fmaf(arow[nn2*4+2], L2g[nn2*64+m], ae);
    ae = fmaf(arow[nn2*4+3], Gm [nn2*64+m], ae);
  }
  Aeff[g*64+m] = ae;
}

// ---------------------------------------------------------------------------
// K4: xp[12800][384] = X[12800][64] @ Aeff[384][64]^T + constv, where
// X[m][k] = x[b][k][t] (m = b*200+t) — transpose FUSED into the staging load
// (lane = row -> consecutive t -> coalesced 256B runs). k3 is eliminated.
// ---------------------------------------------------------------------------
__global__ __launch_bounds__(256) void k4_gemm(
    const float* __restrict__ x, const float* __restrict__ Aeff,
    const float* __restrict__ constv, float* __restrict__ xp)
{
  const int m0 = blockIdx.x*64, g0 = blockIdx.y*64;
  __shared__ float sX[64*68];   // [k][m-row], stride 68
  __shared__ float sA[64*68];   // [k][g-row]
  const int tid = threadIdx.x;

  // ---- stage X tile with fused transpose ----
  {
    const int row = tid & 63;            // lane = row (t-direction)
    const int kq  = tid >> 6;            // 0..3
    const int m = m0 + row;
    const int b = m / 200;
    const int t = m - b*200;
    const float* xb = x + (size_t)b*64*200 + t;
    #pragma unroll
    for (int kk=0; kk<16; ++kk) {
      int k = kq*16 + kk;
      sX[k*68 + row] = xb[(size_t)k*200];
    }
  }
  // ---- stage Aeff tile (float4 loads) ----
  {
    const float4* A4 = (const float4*)Aeff;
    #pragma unroll
    for (int i=0;i<4;i++) {
      int f = tid + i*256;
      int r2 = f >> 4, kq2 = f & 15;
      float4 w = A4[(g0+r2)*16 + kq2];
      sA[(kq2*4+0)*68 + r2] = w.x;
      sA[(kq2*4+1)*68 + r2] = w.y;
      sA[(kq2*4+2)*68 + r2] = w.z;
      sA[(kq2*4+3)*68 + r2] = w.w;
    }
  }
  __syncthreads();

  const int tm = tid & 15, tn = tid >> 4;
  float acc[4][4] = {};
  #pragma unroll 8
  for (int k=0;k<64;k++) {
    float4 a  = *(const float4*)&sX[k*68 + tm*4];
    float4 bb = *(const float4*)&sA[k*68 + tn*4];
    float av[4]={a.x,a.y,a.z,a.w}, bv[4]={bb.x,bb.y,bb.z,bb.w};
    #pragma unroll
    for (int i=0;i<4;i++)
      #pragma unroll
      for (int j=0;j<4;j++)
        acc[i][j] = fmaf(av[i], bv[j], acc[i][j]);
  }

  float cv[4];
  #pragma unroll
  for (int j=0;j<4;j++) cv[j] = constv[g0 + tn*4 + j];
  #pragma unroll
  for (int i=0;i<4;i++) {
    int mrow = m0 + tm*4 + i;
    #pragma unroll
    for (int j=0;j<4;j++)
      xp[mrow*384 + g0 + tn*4 + j] = acc[i][j] + cv[j];
  }
}

// ---------------------------------------------------------------------------
// K5: biGRU recurrence, single wave per (b,dir). Lane g owns hidden unit g.
// h broadcast via LDS (ds_write_b16 + broadcast ds_read_b128). R11 insight:
// all-8-reads-upfront kept 32 hv regs live -> live set ~155 > granted 132
// -> per-step scratch spill on the serial chain. Fix: consume h in 4 chunks
// of 2x ds_read_b128 (peak hv live 16), pinned one-chunk-ahead with
// sched_group_barrier (DS_READ=0x100, VALU=0x2) so chunk c+1's loads issue
// under chunk c's dot2s.
// ---------------------------------------------------------------------------
__global__ __launch_bounds__(64)
__attribute__((amdgpu_waves_per_eu(1, 1)))
void k5_gru(
    const float* __restrict__ xp,
    const float* __restrict__ Whh_f, const float* __restrict__ bhh_f,
    const float* __restrict__ Whh_b, const float* __restrict__ bhh_b,
    float* __restrict__ gru_out)
{
  const int bd = blockIdx.x;
  const int b = bd >> 1, dir = bd & 1;
  const int g = threadIdx.x & 63;
  const float* Whh = dir ? Whh_b : Whh_f;
  const float* bhh = dir ? bhh_b : bhh_f;

  // resident fp16-packed weight rows (3 gate rows for this lane's unit)
  h2v wr[32], wz[32], wn[32];
  #pragma unroll
  for (int i=0;i<32;i++){
    float2 a = ((const float2*)(Whh + (size_t)g*64))[i];
    float2 bq= ((const float2*)(Whh + (size_t)(64+g)*64))[i];
    float2 c = ((const float2*)(Whh + (size_t)(128+g)*64))[i];
    wr[i] = h2v{(_Float16)a.x, (_Float16)a.y};
    wz[i] = h2v{(_Float16)bq.x,(_Float16)bq.y};
    wn[i] = h2v{(_Float16)c.x, (_Float16)c.y};
  }
  const float br_ = bhh[g], bz_ = bhh[64+g], bn_ = bhh[128+g];

  __shared__ __align__(16) _Float16 hsh[64];   // packed fp16 h vector (128 B)
  hsh[g] = (_Float16)0.f;                      // initial h = 0

  const int t0 = dir ? (Tt-1) : 0;
  const int tstep = dir ? -1 : 1;
  const float* xb = xp + (size_t)(b*Tt)*384 + dir*192 + g;
  float* gout = gru_out + (size_t)(b*Tt)*128 + dir*64 + g;

  float h = 0.f;
  float xrA = xb[(size_t)t0*384], xzA = xb[(size_t)t0*384+64], xnA = xb[(size_t)t0*384+128];
  const int t1 = t0 + tstep;
  float xrB = xb[(size_t)t1*384], xzB = xb[(size_t)t1*384+64], xnB = xb[(size_t)t1*384+128];

  int t = t0;
  auto STEP = [&](float& xr, float& xz, float& xn){
    const float cxr = xr, cxz = xz, cxn = xn;
    const int tpre = t + 2*tstep;
    if ((unsigned)tpre < (unsigned)Tt) {   // depth-2 prefetch, reload after use
      xr = xb[(size_t)tpre*384];
      xz = xb[(size_t)tpre*384+64];
      xn = xb[(size_t)tpre*384+128];
    }

    const uint4* hp4 = (const uint4*)hsh;
    union U { uint4 v; h2v p[4]; };
    float ar0=0.f,ar1=0.f,az0=0.f,az1=0.f,an0=0.f,an1=0.f;

#define DOTS8(U0,U1,base)                                                     \
    { _Pragma("unroll")                                                       \
      for (int j=0;j<4;j++){                                                  \
        ar0=DOT2(wr[(base)+j],  U0.p[j],ar0);                                 \
        az0=DOT2(wz[(base)+j],  U0.p[j],az0);                                 \
        an0=DOT2(wn[(base)+j],  U0.p[j],an0);                                 \
        ar1=DOT2(wr[(base)+4+j],U1.p[j],ar1);                                 \
        az1=DOT2(wz[(base)+4+j],U1.p[j],az1);                                 \
        an1=DOT2(wn[(base)+4+j],U1.p[j],an1);                                 \
      } }

    U A0,A1,B0,B1,C0,C1,D0,D1;
    A0.v=hp4[0]; A1.v=hp4[1]; B0.v=hp4[2]; B1.v=hp4[3];
    __builtin_amdgcn_sched_group_barrier(0x100, 4, 0);   // 4 DS_READ
    DOTS8(A0,A1,0);
    __builtin_amdgcn_sched_group_barrier(0x2, 24, 0);    // 24 VALU (chunk0)
    C0.v=hp4[4]; C1.v=hp4[5];
    __builtin_amdgcn_sched_group_barrier(0x100, 2, 0);
    DOTS8(B0,B1,8);
    __builtin_amdgcn_sched_group_barrier(0x2, 24, 0);
    D0.v=hp4[6]; D1.v=hp4[7];
    __builtin_amdgcn_sched_group_barrier(0x100, 2, 0);
    DOTS8(C0,C1,16);
    __builtin_amdgcn_sched_group_barrier(0x2, 24, 0);
    DOTS8(D0,D1,24);
    __builtin_amdgcn_sched_group_barrier(0x2, 24, 0);
#undef DOTS8

    float r   = sigm(cxr + (ar0+ar1) + br_);
    float z   = sigm(cxz + (az0+az1) + bz_);
    float nn2 = tanh_fast(cxn + r*((an0+an1) + bn_));
    float hnew = (1.f - z)*nn2 + z*h;
    h = hnew;
    hsh[g] = (_Float16)hnew;               // ds_write_b16 for next step
    gout[(size_t)t*128] = hnew;
    t += tstep;
  };

  for (int sp=0; sp<Tt; sp+=2) { STEP(xrA,xzA,xnA); STEP(xrB,xzB,xnB); }
}

// ---------------------------------------------------------------------------
// K6: attention pooling + classifier. One block per batch item.
// ---------------------------------------------------------------------------
__global__ __launch_bounds__(256) void k6_attn(
    const float* __restrict__ gru_out,
    const float* __restrict__ attn_W, const float* __restrict__ attn_b,
    const float* __restrict__ clf_W,  const float* __restrict__ clf_b,
    float* __restrict__ out)
{
  const int b = blockIdx.x, tid = threadIdx.x;
  __shared__ float s_s[Tt];
  __shared__ float red[256];
  __shared__ float aW[128], cW[128];
  if (tid < 128) { aW[tid]=attn_W[tid]; cW[tid]=clf_W[tid]; }
  __syncthreads();

  if (tid < Tt) {
    const float* row = gru_out + (b*Tt + tid)*128;
    float acc = 0.f;
    for (int j=0;j<128;j++) acc = fmaf(row[j], aW[j], acc);
    s_s[tid] = tanhf(acc + attn_b[0]);
  }
  __syncthreads();

  red[tid] = (tid < Tt) ? s_s[tid] : -1e30f;
  __syncthreads();
  for (int s2=128;s2;s2>>=1){ if(tid<s2) red[tid]=fmaxf(red[tid],red[tid+s2]); __syncthreads(); }
  float mx = red[0];
  __syncthreads();

  float e = 0.f;
  if (tid < Tt) { e = expf(s_s[tid]-mx); s_s[tid] = e; }
  red[tid] = e;
  __syncthreads();
  for (int s2=128;s2;s2>>=1){ if(tid<s2) red[tid]+=red[tid+s2]; __syncthreads(); }
  float total = red[0];
  __syncthreads();

  float p = 0.f;
  if (tid < 128) {
    float c = 0.f;
    for (int t=0;t<Tt;t++) c = fmaf(s_s[t], gru_out[(b*Tt+t)*128 + tid], c);
    p = (c/total)*cW[tid];
  }
  red[tid] = p;
  __syncthreads();
  for (int s2=128;s2;s2>>=1){ if(tid<s2) red[tid]+=red[tid+s2]; __syncthreads(); }
  if (tid==0) out[b] = sigm(red[0] + clf_b[0]);
}

// ---------------------------------------------------------------------------
extern "C" void kernel_launch(void* const* d_in, const int* in_sizes, int n_in,
                              void* d_out, int out_size, void* d_ws, size_t ws_size,
                              hipStream_t stream)
{
  const float* x      = (const float*)d_in[0];
  const int*   sp_ei  = (const int*)  d_in[1];
  const float* sp_ew  = (const float*)d_in[2];
  const int*   fn_ei  = (const int*)  d_in[3];
  const float* fn_ew  = (const float*)d_in[4];
  const float* Wcheb  = (const float*)d_in[5];
  const float* bcheb  = (const float*)d_in[6];
  const float* Wgcn   = (const float*)d_in[7];
  const float* bgcn   = (const float*)d_in[8];
  const float* Wih_f  = (const float*)d_in[9];
  const float* Whh_f  = (const float*)d_in[10];
  const float* bih_f  = (const float*)d_in[11];
  const float* bhh_f  = (const float*)d_in[12];
  const float* Wih_b  = (const float*)d_in[13];
  const float* Whh_b  = (const float*)d_in[14];
  const float* bih_b  = (const float*)d_in[15];
  const float* bhh_b  = (const float*)d_in[16];
  const float* attn_W = (const float*)d_in[17];
  const float* attn_b = (const float*)d_in[18];
  const float* clf_W  = (const float*)d_in[19];
  const float* clf_b  = (const float*)d_in[20];
  float* out = (float*)d_out;

  float* ws     = (float*)d_ws;
  float* Lg     = ws;                    // 4096
  float* L2g    = Lg   + 4096;           // 4096
  float* Gm     = L2g  + 4096;           // 4096
  float* Aeff   = Gm   + 4096;           // 384*64 = 24576
  float* constv = Aeff + 24576;          // 384 (+pad to 512)
  float* xp     = constv + 512;          // 12800*384 = 4915200
  float* gro    = xp   + 4915200;        // 12800*128 = 1638400

  hipLaunchKernelGGL(k1_graphs,    dim3(1),      dim3(256), 0, stream,
                     sp_ei, sp_ew, fn_ei, fn_ew, Lg, L2g, Gm);
  hipLaunchKernelGGL(k2_aeff,      dim3(384),    dim3(64),  0, stream,
                     Wih_f, bih_f, Wih_b, bih_b, Wcheb, bcheb, Wgcn, bgcn,
                     Lg, L2g, Gm, Aeff, constv);
  hipLaunchKernelGGL(k4_gemm,      dim3(200, 6), dim3(256), 0, stream,
                     x, Aeff, constv, xp);
  hipLaunchKernelGGL(k5_gru,       dim3(128),    dim3(64),  0, stream,
                     xp, Whh_f, bhh_f, Whh_b, bhh_b, gro);
  hipLaunchKernelGGL(k6_attn,      dim3(64),     dim3(256), 0, stream,
                     gro, attn_W, attn_b, clf_W, clf_b, out);
}